// Round 6
// baseline (374.879 us; speedup 1.0000x reference)
//
#include <hip/hip_runtime.h>
#include <cstddef>

#define NB 32
#define NN 2000
#define NRD 32
#define NE 128
#define NH 256
#define NA 8
#define KP 2016          // conv K padded to multiple of 32
#define NGP 256          // node-pair groups per batch in k_agent
#define ACTION_NORM 2000.0f

typedef unsigned short u16;
typedef __bf16 b16x8 __attribute__((ext_vector_type(8)));
typedef float f32x4 __attribute__((ext_vector_type(4)));
typedef const __attribute__((address_space(1))) unsigned int* gptr_t;
typedef __attribute__((address_space(3))) unsigned int* lptr_t;

__device__ inline u16 f2bf(float x) {
    unsigned u = __float_as_uint(x);
    u += 0x7FFFu + ((u >> 16) & 1u);
    return (u16)(u >> 16);
}
__device__ inline float bf2f(u16 h) { return __uint_as_float((unsigned)h << 16); }

// ---------------------------------------------------------------- init: dmax reset + actions
__global__ __launch_bounds__(256) void k_init(unsigned* dmax_u, float* actions,
                                              const int* __restrict__ fa,
                                              const int* __restrict__ fid) {
    const int t = threadIdx.x;            // t = b*8 + a
    if (t == 0) *dmax_u = 0u;
    const int b = t >> 3, a = t & 7;
    float v = -1.0f;
    for (int j = 0; j < 3; ++j)
        if (fid[j] == a) v = (float)fa[j * NB + b] / ACTION_NORM;
    actions[t] = v;
}

// ---------------------------------------------------------------- global max of dm
__global__ __launch_bounds__(256) void k_max(const float* __restrict__ dm,
                                             unsigned* dmax_u, int n) {
    __shared__ float sh[256];
    float m = 0.0f;
    for (int i = blockIdx.x * blockDim.x + threadIdx.x; i < n; i += gridDim.x * blockDim.x)
        m = fmaxf(m, dm[i]);
    sh[threadIdx.x] = m; __syncthreads();
    for (int s = 128; s > 0; s >>= 1) {
        if (threadIdx.x < s) sh[threadIdx.x] = fmaxf(sh[threadIdx.x], sh[threadIdx.x + s]);
        __syncthreads();
    }
    if (threadIdx.x == 0) atomicMax(dmax_u, __float_as_uint(sh[0]));
}

// ---------------------------------------------------------------- sim rows -> bf16 (K padded), inv rowsum
__global__ __launch_bounds__(256) void k_sim(const float* __restrict__ dm,
                                             const unsigned* __restrict__ dmax_u,
                                             u16* __restrict__ simb,
                                             float* __restrict__ inv_rs) {
    __shared__ float sh[256];
    const int n = blockIdx.x;
    const float inv = 1.0f / __uint_as_float(*dmax_u);
    float s = 0.0f;
    for (int m = threadIdx.x; m < KP; m += 256) {
        if (m < NN) {
            float e = expf(-dm[(size_t)n * NN + m] * inv);
            simb[(size_t)n * KP + m] = f2bf(e);
            s += e;
        } else {
            simb[(size_t)n * KP + m] = 0;
        }
    }
    sh[threadIdx.x] = s; __syncthreads();
    for (int st = 128; st > 0; st >>= 1) {
        if (threadIdx.x < st) sh[threadIdx.x] += sh[threadIdx.x + st];
        __syncthreads();
    }
    if (threadIdx.x == 0) inv_rs[n] = 1.0f / sh[0];
}

// ---------------------------------------------------------------- prep: convert state, transpose weights, zero ENC pad
#define PREP_STATE (64000 * 32)
#define PREP_W1T   (256 * 32)
#define PREP_W2T   (128 * 256)
#define PREP_WQ1T  (256 * 128)
#define PREP_PAD   (4096 * 16)
#define PREP_TOT   (PREP_STATE + PREP_W1T + PREP_W2T + PREP_WQ1T + PREP_PAD)
__global__ __launch_bounds__(256) void k_prep(const float* __restrict__ state,
                                              const float* __restrict__ W1,
                                              const float* __restrict__ W2,
                                              const float* __restrict__ Wq1,
                                              u16* __restrict__ state_b, u16* __restrict__ W1t,
                                              u16* __restrict__ W2t, u16* __restrict__ Wq1at,
                                              u16* __restrict__ ENCt) {
    int i = blockIdx.x * 256 + threadIdx.x;
    if (i < PREP_STATE) { state_b[i] = f2bf(state[i]); return; }
    i -= PREP_STATE;
    if (i < PREP_W1T) { int h = i >> 5, k = i & 31; W1t[i] = f2bf(W1[k * NH + h]); return; }
    i -= PREP_W1T;
    if (i < PREP_W2T) { int e = i >> 8, h = i & 255; W2t[i] = f2bf(W2[h * NE + e]); return; }
    i -= PREP_W2T;
    if (i < PREP_WQ1T) { int hq = i >> 7, e = i & 127; Wq1at[i] = f2bf(Wq1[e * NH + hq]); return; }
    i -= PREP_WQ1T;
    if (i < PREP_PAD) { int eb = i >> 4, mm = NN + (i & 15); ENCt[(size_t)eb * KP + mm] = 0; }
}

// ---------------------------------------------------------------- bf16 NT MFMA GEMM, 128x128 tile, BK=32
// C = A[M][K] * (Bt[N][K])^T ; out bf16. BMODE: 0 none, 1 bias[col], 2 bias[row].
// PERM (enc2): col=(b*2000+m) -> ((b*128 + row)*KP + m)  [(b,e) row order]
template<int RELU, int BMODE, int PERM>
__global__ __launch_bounds__(256) void mfma_gemm(
        const u16* __restrict__ A, const u16* __restrict__ Bt, u16* __restrict__ C,
        int M, int N, int K, int lda, int ldb, int ldc,
        const float* __restrict__ bias) {
    __shared__ u16 lds[16 * 512];           // 16 chunks x 1KB (A: 0-7, B: 8-15)
    const int tid = threadIdx.x;
    const int w = tid >> 6, l = tid & 63;
    const int wr = w & 1, wc = w >> 1;
    const int bm = blockIdx.x * 128, bn = blockIdx.y * 128;
    const int lm = l & 15, lq = l >> 4;

    f32x4 acc[4][4] = {};

    for (int k0 = 0; k0 < K; k0 += 32) {
        __syncthreads();
#pragma unroll
        for (int i = 0; i < 4; ++i) {
            const int idx = w * 4 + i;
            const u16* gp;
            if (idx < 8) {
                int row = bm + idx * 16 + lm;
                row = row < M ? row : M - 1;
                gp = A + (size_t)row * lda + k0 + lq * 8;
            } else {
                const int col = bn + (idx - 8) * 16 + lm;
                gp = Bt + (size_t)col * ldb + k0 + lq * 8;
            }
            __builtin_amdgcn_global_load_lds((gptr_t)gp, (lptr_t)(lds + idx * 512), 16, 0, 0);
        }
        __syncthreads();
        b16x8 af[4], bf[4];
#pragma unroll
        for (int i = 0; i < 4; ++i) {
            af[i] = *(const b16x8*)(lds + (wr * 4 + i) * 512 + l * 8);
            bf[i] = *(const b16x8*)(lds + (8 + wc * 4 + i) * 512 + l * 8);
        }
#pragma unroll
        for (int fr = 0; fr < 4; ++fr)
#pragma unroll
            for (int fc = 0; fc < 4; ++fc)
                acc[fr][fc] = __builtin_amdgcn_mfma_f32_16x16x32_bf16(af[fr], bf[fc], acc[fr][fc], 0, 0, 0);
    }

#pragma unroll
    for (int fr = 0; fr < 4; ++fr) {
#pragma unroll
        for (int r = 0; r < 4; ++r) {
            const int row = bm + wr * 64 + fr * 16 + lq * 4 + r;
            if (row >= M) continue;
#pragma unroll
            for (int fc = 0; fc < 4; ++fc) {
                const int col = bn + wc * 64 + fc * 16 + lm;
                float v = acc[fr][fc][r];
                if (BMODE == 1) v += bias[col];
                if (BMODE == 2) v += bias[row];
                if (RELU) v = fmaxf(v, 0.0f);
                size_t addr;
                if (PERM) {
                    const unsigned bb = (unsigned)col / 2000u;
                    const unsigned mm = (unsigned)col - bb * 2000u;
                    addr = ((size_t)bb * 128 + row) * KP + mm;
                } else {
                    addr = (size_t)row * ldc + col;
                }
                C[addr] = f2bf(v);
            }
        }
    }
}

// ---------------------------------------------------------------- fused conv + y0 projection
// grid (16, 32): block = (node-tile bm, batch bb).
// Phase 1: X[128n][128e] = inv_rs * (simb @ ENCt[bb]^T)  -> LDS (stride 136)
// Phase 2: y0[128n][256h] = X @ Wq1at^T + bq1            -> global [(n*32+b)][h]
__global__ __launch_bounds__(256) void k_conv_y0(
        const u16* __restrict__ simb, const u16* __restrict__ ENCt,
        const u16* __restrict__ Wq1at, const float* __restrict__ inv_rs,
        const float* __restrict__ bq1, u16* __restrict__ y0w) {
    __shared__ u16 lds[16 * 512];           // 16 KB staging
    __shared__ u16 xt[128 * 136];           // 34 KB X tile (padded stride)
    const int tid = threadIdx.x;
    const int w = tid >> 6, l = tid & 63;
    const int wr = w & 1, wc = w >> 1;
    const int bm = blockIdx.x * 128;        // node tile base
    const int bb = blockIdx.y;              // batch
    const int lm = l & 15, lq = l >> 4;
    const u16* Bt = ENCt + (size_t)bb * 128 * KP;

    f32x4 acc[4][4] = {};
    for (int k0 = 0; k0 < KP; k0 += 32) {
        __syncthreads();
#pragma unroll
        for (int i = 0; i < 4; ++i) {
            const int idx = w * 4 + i;
            const u16* gp;
            if (idx < 8) {
                int row = bm + idx * 16 + lm;
                row = row < NN ? row : NN - 1;
                gp = simb + (size_t)row * KP + k0 + lq * 8;
            } else {
                gp = Bt + (size_t)((idx - 8) * 16 + lm) * KP + k0 + lq * 8;
            }
            __builtin_amdgcn_global_load_lds((gptr_t)gp, (lptr_t)(lds + idx * 512), 16, 0, 0);
        }
        __syncthreads();
        b16x8 af[4], bf[4];
#pragma unroll
        for (int i = 0; i < 4; ++i) {
            af[i] = *(const b16x8*)(lds + (wr * 4 + i) * 512 + l * 8);
            bf[i] = *(const b16x8*)(lds + (8 + wc * 4 + i) * 512 + l * 8);
        }
#pragma unroll
        for (int fr = 0; fr < 4; ++fr)
#pragma unroll
            for (int fc = 0; fc < 4; ++fc)
                acc[fr][fc] = __builtin_amdgcn_mfma_f32_16x16x32_bf16(af[fr], bf[fc], acc[fr][fc], 0, 0, 0);
    }

    // ---- epilogue 1: scaled X tile into LDS
    __syncthreads();
#pragma unroll
    for (int fr = 0; fr < 4; ++fr) {
#pragma unroll
        for (int r = 0; r < 4; ++r) {
            const int row = wr * 64 + fr * 16 + lq * 4 + r;
            const int gn = bm + row;
            const float rsv = inv_rs[gn < NN ? gn : NN - 1];
#pragma unroll
            for (int fc = 0; fc < 4; ++fc) {
                const int col = wc * 64 + fc * 16 + lm;
                xt[row * 136 + col] = f2bf(acc[fr][fc][r] * rsv);
            }
        }
    }
    __syncthreads();

    // ---- phase 2: y0 tile; wave w handles h-cols [w*64, w*64+64)
    f32x4 acc2[8][4] = {};
#pragma unroll
    for (int ks = 0; ks < 4; ++ks) {
        b16x8 bf2[4];
#pragma unroll
        for (int j = 0; j < 4; ++j)
            bf2[j] = *(const b16x8*)(Wq1at + (size_t)(w * 64 + j * 16 + lm) * NE + ks * 32 + lq * 8);
#pragma unroll
        for (int i = 0; i < 8; ++i) {
            const b16x8 af2 = *(const b16x8*)(xt + (i * 16 + lm) * 136 + ks * 32 + lq * 8);
#pragma unroll
            for (int j = 0; j < 4; ++j)
                acc2[i][j] = __builtin_amdgcn_mfma_f32_16x16x32_bf16(af2, bf2[j], acc2[i][j], 0, 0, 0);
        }
    }
#pragma unroll
    for (int i = 0; i < 8; ++i) {
#pragma unroll
        for (int r = 0; r < 4; ++r) {
            const int n = bm + i * 16 + lq * 4 + r;
            if (n >= NN) continue;
#pragma unroll
            for (int j = 0; j < 4; ++j) {
                const int col = w * 64 + j * 16 + lm;
                y0w[((size_t)n * NB + bb) * NH + col] = f2bf(acc2[i][j][r] + bq1[col]);
            }
        }
    }
}

// ---------------------------------------------------------------- per-agent kernel
// grid 2048x256 = 8192 waves; wave wg: b=wg&31, ng=wg>>5 (0..255).
// Wave handles node PAIRS p = ng+256k (rows 2p, 2p+1 via half-waves, uint4 loads).
// Every wave recomputes sam(ag-1) from pin (bit-identical); one float2 out, no atomics.
// Blocks 0..31 additionally finalize agent ag-1.
__global__ __launch_bounds__(256) void k_agent(
        const u16* __restrict__ y0, const float* __restrict__ Wq1,
        const float* __restrict__ Wq2, const float* __restrict__ bq2,
        float* actions, const float2* __restrict__ pin, float2* __restrict__ pout,
        float* __restrict__ out, int ag) {
    __shared__ float sh[256];
    __shared__ float s_sam;
    const int t = threadIdx.x;
    const int lane = t & 63, wave = t >> 6;
    const int wg = blockIdx.x * 4 + wave;
    const int b = wg & 31, ng = wg >> 5;        // ng in [0,256)
    const int hl = lane & 31, half = lane >> 5;

    float act[NA];
#pragma unroll
    for (int a = 0; a < NA; ++a) act[a] = actions[b * NA + a];
    if (ag > 0) {
        const float2 p0 = pin[b * NGP + lane];
        const float2 p1 = pin[b * NGP + 64 + lane];
        const float2 p2 = pin[b * NGP + 128 + lane];
        const float2 p3 = pin[b * NGP + 192 + lane];
        float se0 = p0.x + p1.x + p2.x + p3.x;
        float sn0 = p0.y + p1.y + p2.y + p3.y;
#pragma unroll
        for (int m = 32; m > 0; m >>= 1) {
            se0 += __shfl_xor(se0, m); sn0 += __shfl_xor(sn0, m);
        }
        const float sam = fminf(fmaxf(sn0 / se0, 0.0f), 2000.0f);
        act[ag - 1] = sam * (1.0f / ACTION_NORM);
    }
    // ap slice (8 elements) and w2 slice for this half-lane
    float ap8[8] = {};
#pragma unroll
    for (int a = 0; a < NA; ++a) {
        const float4 wqa = *(const float4*)(Wq1 + (size_t)(NE + a) * NH + hl * 8);
        const float4 wqb = *(const float4*)(Wq1 + (size_t)(NE + a) * NH + hl * 8 + 4);
        ap8[0] = fmaf(act[a], wqa.x, ap8[0]); ap8[1] = fmaf(act[a], wqa.y, ap8[1]);
        ap8[2] = fmaf(act[a], wqa.z, ap8[2]); ap8[3] = fmaf(act[a], wqa.w, ap8[3]);
        ap8[4] = fmaf(act[a], wqb.x, ap8[4]); ap8[5] = fmaf(act[a], wqb.y, ap8[5]);
        ap8[6] = fmaf(act[a], wqb.z, ap8[6]); ap8[7] = fmaf(act[a], wqb.w, ap8[7]);
    }
    const float4 w2a = *(const float4*)(Wq2 + hl * 8);
    const float4 w2b = *(const float4*)(Wq2 + hl * 8 + 4);
    const float w2v[8] = {w2a.x, w2a.y, w2a.z, w2a.w, w2b.x, w2b.y, w2b.z, w2b.w};

    float se = 0.0f, sn = 0.0f;
    for (int p = ng; p < NN / 2; p += NGP) {
        const int n = 2 * p + half;
        const uint4 yv = *(const uint4*)(y0 + ((size_t)n * NB + b) * NH + hl * 8);
        const unsigned uu[4] = {yv.x, yv.y, yv.z, yv.w};
        float q = 0.0f;
#pragma unroll
        for (int j = 0; j < 4; ++j) {
            q += fmaxf(__uint_as_float(uu[j] << 16) + ap8[2 * j], 0.f) * w2v[2 * j];
            q += fmaxf(__uint_as_float(uu[j] & 0xFFFF0000u) + ap8[2 * j + 1], 0.f) * w2v[2 * j + 1];
        }
#pragma unroll
        for (int off = 16; off > 0; off >>= 1) q += __shfl_xor(q, off);
        if (hl == 0) {
            const float e = expf(fminf(q, 60.0f));
            se += e; sn += e * (float)n;
        }
    }
    se += __shfl_xor(se, 32); sn += __shfl_xor(sn, 32);
    if (lane == 0) pout[b * NGP + ng] = make_float2(se, sn);

    if (ag > 0 && blockIdx.x < NB) {
        const int bb = blockIdx.x;
        if (wave == 0) {
            const float2 p0 = pin[bb * NGP + lane];
            const float2 p1 = pin[bb * NGP + 64 + lane];
            const float2 p2 = pin[bb * NGP + 128 + lane];
            const float2 p3 = pin[bb * NGP + 192 + lane];
            float a1 = p0.x + p1.x + p2.x + p3.x;
            float a2 = p0.y + p1.y + p2.y + p3.y;
#pragma unroll
            for (int m = 32; m > 0; m >>= 1) {
                a1 += __shfl_xor(a1, m); a2 += __shfl_xor(a2, m);
            }
            if (lane == 0) s_sam = fminf(fmaxf(a2 / a1, 0.0f), 2000.0f);
        }
        __syncthreads();
        const float sam = s_sam;
        const float samn = sam * (1.0f / ACTION_NORM);
        float apt = 0.0f;
#pragma unroll
        for (int a = 0; a < NA; ++a) {
            const float av = (a == ag - 1) ? samn : actions[bb * NA + a];
            apt = fmaf(av, Wq1[(size_t)(NE + a) * NH + t], apt);
        }
        int nsel = (int)sam; if (nsel > NN - 1) nsel = NN - 1;
        const float yv = bf2f(y0[((size_t)nsel * NB + bb) * NH + t]);
        sh[t] = fmaxf(yv + apt, 0.0f) * Wq2[t];
        __syncthreads();
        for (int s = 128; s > 0; s >>= 1) {
            if (t < s) sh[t] += sh[t + s];
            __syncthreads();
        }
        if (t == 0) {
            out[bb * NA + (ag - 1)] = sh[0] + bq2[0];
            actions[bb * NA + (ag - 1)] = samn;
        }
    }
}

// ---------------------------------------------------------------- tail: finalize agent 7 + chosen
__global__ __launch_bounds__(256) void k_fin(
        const u16* __restrict__ y0, const float* __restrict__ Wq1,
        const float* __restrict__ Wq2, const float* __restrict__ bq2,
        const float* __restrict__ actions, const float2* __restrict__ pin,
        float* __restrict__ out) {
    __shared__ float sh[256];
    __shared__ float s_sam;
    const int bb = blockIdx.x, t = threadIdx.x;
    const int lane = t & 63, wave = t >> 6;
    if (wave == 0) {
        const float2 p0 = pin[bb * NGP + lane];
        const float2 p1 = pin[bb * NGP + 64 + lane];
        const float2 p2 = pin[bb * NGP + 128 + lane];
        const float2 p3 = pin[bb * NGP + 192 + lane];
        float a1 = p0.x + p1.x + p2.x + p3.x;
        float a2 = p0.y + p1.y + p2.y + p3.y;
#pragma unroll
        for (int m = 32; m > 0; m >>= 1) {
            a1 += __shfl_xor(a1, m); a2 += __shfl_xor(a2, m);
        }
        if (lane == 0) s_sam = fminf(fmaxf(a2 / a1, 0.0f), 2000.0f);
    }
    __syncthreads();
    const float sam = s_sam;
    const float samn = sam * (1.0f / ACTION_NORM);
    float apt = 0.0f;
#pragma unroll
    for (int a = 0; a < NA; ++a) {
        const float av = (a == NA - 1) ? samn : actions[bb * NA + a];
        apt = fmaf(av, Wq1[(size_t)(NE + a) * NH + t], apt);
    }
    int nsel = (int)sam; if (nsel > NN - 1) nsel = NN - 1;
    const float yv = bf2f(y0[((size_t)nsel * NB + bb) * NH + t]);
    sh[t] = fmaxf(yv + apt, 0.0f) * Wq2[t];
    __syncthreads();
    for (int s = 128; s > 0; s >>= 1) {
        if (t < s) sh[t] += sh[t + s];
        __syncthreads();
    }
    if (t == 0) out[bb * NA + (NA - 1)] = sh[0] + bq2[0];
    if (t < NA) {
        const float av = (t == NA - 1) ? samn : actions[bb * NA + t];
        out[NB * NA + bb * NA + t] = (float)(int)(av * ACTION_NORM);
    }
}

// ---------------------------------------------------------------- launch
extern "C" void kernel_launch(void* const* d_in, const int* in_sizes, int n_in,
                              void* d_out, int out_size, void* d_ws, size_t ws_size,
                              hipStream_t stream) {
    const float* state = (const float*)d_in[0];
    const float* dm    = (const float*)d_in[1];
    const float* W1    = (const float*)d_in[2];
    const float* b1    = (const float*)d_in[3];
    const float* W2    = (const float*)d_in[4];
    const float* b2    = (const float*)d_in[5];
    const float* Wq1   = (const float*)d_in[6];
    const float* bq1   = (const float*)d_in[7];
    const float* Wq2   = (const float*)d_in[8];
    const float* bq2   = (const float*)d_in[9];
    const int* fa      = (const int*)d_in[10];
    const int* fid     = (const int*)d_in[11];
    float* out = (float*)d_out;

    char* p = (char*)d_ws;
    u16* simb      = (u16*)p;      p += (size_t)NN * KP * 2;        // 8.06 MB
    float* inv_rs  = (float*)p;    p += 2048 * 4;
    unsigned* dmax_u = (unsigned*)p; p += 256;
    float* actions = (float*)p;    p += 256 * 4;
    float2* part0  = (float2*)p;   p += (size_t)NB * NGP * 8;
    float2* part1  = (float2*)p;   p += (size_t)NB * NGP * 8;
    u16* state_b   = (u16*)p;      p += (size_t)2048000 * 2;
    u16* W1t       = (u16*)p;      p += 8192 * 2;
    u16* W2t       = (u16*)p;      p += 32768 * 2;
    u16* Wq1at     = (u16*)p;      p += 32768 * 2;
    u16* h1        = (u16*)p;      p += (size_t)16384000 * 2;       // 32.8 MB
    u16* ENCt      = (u16*)p;      p += (size_t)4096 * KP * 2;      // 16.5 MB
    u16* y0w       = (u16*)p;      p += (size_t)16384000 * 2;       // 32.8 MB

    const int RTOT = NB * NN;  // 64000

    k_prep<<<(PREP_TOT + 255) / 256, 256, 0, stream>>>(state, W1, W2, Wq1,
                                                       state_b, W1t, W2t, Wq1at, ENCt);
    k_init<<<1, 256, 0, stream>>>(dmax_u, actions, fa, fid);
    k_max<<<1024, 256, 0, stream>>>(dm, dmax_u, NN * NN);
    k_sim<<<NN, 256, 0, stream>>>(dm, dmax_u, simb, inv_rs);

    // enc1: h1 = relu(state @ W1 + b1)  [64000,256]
    mfma_gemm<1, 1, 0><<<dim3(RTOT / 128, NH / 128), 256, 0, stream>>>(
        state_b, W1t, h1, RTOT, NH, NRD, NRD, NRD, NH, b1);
    // enc2 (transposed out, (b,e) rows): ENCt[(b,e)][m] = (W2t @ h1^T) + b2[row]
    mfma_gemm<0, 2, 1><<<dim3(1, RTOT / 128), 256, 0, stream>>>(
        W2t, h1, ENCt, NE, RTOT, NH, NH, NH, 0, b2);
    // fused conv + y0: per (node-tile, batch) block
    k_conv_y0<<<dim3(16, 32), 256, 0, stream>>>(simb, ENCt, Wq1at, inv_rs, bq1, y0w);

    // 8-agent loop: one kernel per agent, double-buffered partials
    for (int ag = 0; ag < NA; ++ag) {
        const float2* pin  = (ag & 1) ? part0 : part1;
        float2*       pout = (ag & 1) ? part1 : part0;
        k_agent<<<2048, 256, 0, stream>>>(y0w, Wq1, Wq2, bq2, actions,
                                          pin, pout, out, ag);
    }
    // finalize agent 7 (+ chosen); ag=7 wrote part1
    k_fin<<<NB, 256, 0, stream>>>(y0w, Wq1, Wq2, bq2, actions, part1, out);
}

// Round 7
// 313.103 us; speedup vs baseline: 1.1973x; 1.1973x over previous
//
#include <hip/hip_runtime.h>
#include <cstddef>

#define NB 32
#define NN 2000
#define NRD 32
#define NE 128
#define NH 256
#define NA 8
#define KP 2016          // conv K padded to multiple of 32
#define NGP 256          // node-pair groups per batch in k_agent
#define ACTION_NORM 2000.0f

typedef unsigned short u16;
typedef __bf16 b16x8 __attribute__((ext_vector_type(8)));
typedef float f32x4 __attribute__((ext_vector_type(4)));
typedef const __attribute__((address_space(1))) unsigned int* gptr_t;
typedef __attribute__((address_space(3))) unsigned int* lptr_t;

__device__ inline u16 f2bf(float x) {
    unsigned u = __float_as_uint(x);
    u += 0x7FFFu + ((u >> 16) & 1u);
    return (u16)(u >> 16);
}
__device__ inline float bf2f(u16 h) { return __uint_as_float((unsigned)h << 16); }

// ---------------------------------------------------------------- init: dmax reset + actions
__global__ __launch_bounds__(256) void k_init(unsigned* dmax_u, float* actions,
                                              const int* __restrict__ fa,
                                              const int* __restrict__ fid) {
    const int t = threadIdx.x;            // t = b*8 + a
    if (t == 0) *dmax_u = 0u;
    const int b = t >> 3, a = t & 7;
    float v = -1.0f;
    for (int j = 0; j < 3; ++j)
        if (fid[j] == a) v = (float)fa[j * NB + b] / ACTION_NORM;
    actions[t] = v;
}

// ---------------------------------------------------------------- global max of dm
__global__ __launch_bounds__(256) void k_max(const float* __restrict__ dm,
                                             unsigned* dmax_u, int n) {
    __shared__ float sh[256];
    float m = 0.0f;
    for (int i = blockIdx.x * blockDim.x + threadIdx.x; i < n; i += gridDim.x * blockDim.x)
        m = fmaxf(m, dm[i]);
    sh[threadIdx.x] = m; __syncthreads();
    for (int s = 128; s > 0; s >>= 1) {
        if (threadIdx.x < s) sh[threadIdx.x] = fmaxf(sh[threadIdx.x], sh[threadIdx.x + s]);
        __syncthreads();
    }
    if (threadIdx.x == 0) atomicMax(dmax_u, __float_as_uint(sh[0]));
}

// ---------------------------------------------------------------- sim rows -> bf16 (K padded), inv rowsum
__global__ __launch_bounds__(256) void k_sim(const float* __restrict__ dm,
                                             const unsigned* __restrict__ dmax_u,
                                             u16* __restrict__ simb,
                                             float* __restrict__ inv_rs) {
    __shared__ float sh[256];
    const int n = blockIdx.x;
    const float inv = 1.0f / __uint_as_float(*dmax_u);
    float s = 0.0f;
    for (int m = threadIdx.x; m < KP; m += 256) {
        if (m < NN) {
            float e = expf(-dm[(size_t)n * NN + m] * inv);
            simb[(size_t)n * KP + m] = f2bf(e);
            s += e;
        } else {
            simb[(size_t)n * KP + m] = 0;
        }
    }
    sh[threadIdx.x] = s; __syncthreads();
    for (int st = 128; st > 0; st >>= 1) {
        if (threadIdx.x < st) sh[threadIdx.x] += sh[threadIdx.x + st];
        __syncthreads();
    }
    if (threadIdx.x == 0) inv_rs[n] = 1.0f / sh[0];
}

// ---------------------------------------------------------------- prep: convert state, transpose weights, zero ENC pad
#define PREP_STATE (64000 * 32)
#define PREP_W1T   (256 * 32)
#define PREP_W2T   (128 * 256)
#define PREP_WQ1T  (256 * 128)
#define PREP_PAD   (4096 * 16)
#define PREP_TOT   (PREP_STATE + PREP_W1T + PREP_W2T + PREP_WQ1T + PREP_PAD)
__global__ __launch_bounds__(256) void k_prep(const float* __restrict__ state,
                                              const float* __restrict__ W1,
                                              const float* __restrict__ W2,
                                              const float* __restrict__ Wq1,
                                              u16* __restrict__ state_b, u16* __restrict__ W1t,
                                              u16* __restrict__ W2t, u16* __restrict__ Wq1at,
                                              u16* __restrict__ ENCt) {
    int i = blockIdx.x * 256 + threadIdx.x;
    if (i < PREP_STATE) { state_b[i] = f2bf(state[i]); return; }
    i -= PREP_STATE;
    if (i < PREP_W1T) { int h = i >> 5, k = i & 31; W1t[i] = f2bf(W1[k * NH + h]); return; }
    i -= PREP_W1T;
    if (i < PREP_W2T) { int e = i >> 8, h = i & 255; W2t[i] = f2bf(W2[h * NE + e]); return; }
    i -= PREP_W2T;
    if (i < PREP_WQ1T) { int hq = i >> 7, e = i & 127; Wq1at[i] = f2bf(Wq1[e * NH + hq]); return; }
    i -= PREP_WQ1T;
    if (i < PREP_PAD) { int eb = i >> 4, mm = NN + (i & 15); ENCt[(size_t)eb * KP + mm] = 0; }
}

// ---------------------------------------------------------------- bf16 NT MFMA GEMM, 128x128 tile, BK=32, 256 threads
// C = A[M][K] * (Bt[N][K])^T ; out bf16. BMODE: 0 none, 1 bias[col], 2 bias[row].
// PERM (enc2): col=(b*2000+m) -> ((b*128 + row)*KP + m)  [(b,e) row order]
template<int RELU, int BMODE, int PERM>
__global__ __launch_bounds__(256) void mfma_gemm(
        const u16* __restrict__ A, const u16* __restrict__ Bt, u16* __restrict__ C,
        int M, int N, int K, int lda, int ldb, int ldc,
        const float* __restrict__ bias) {
    __shared__ u16 lds[16 * 512];           // 16 chunks x 1KB (A: 0-7, B: 8-15)
    const int tid = threadIdx.x;
    const int w = tid >> 6, l = tid & 63;
    const int wr = w & 1, wc = w >> 1;
    const int bm = blockIdx.x * 128, bn = blockIdx.y * 128;
    const int lm = l & 15, lq = l >> 4;

    f32x4 acc[4][4] = {};

    for (int k0 = 0; k0 < K; k0 += 32) {
        __syncthreads();
#pragma unroll
        for (int i = 0; i < 4; ++i) {
            const int idx = w * 4 + i;
            const u16* gp;
            if (idx < 8) {
                int row = bm + idx * 16 + lm;
                row = row < M ? row : M - 1;
                gp = A + (size_t)row * lda + k0 + lq * 8;
            } else {
                const int col = bn + (idx - 8) * 16 + lm;
                gp = Bt + (size_t)col * ldb + k0 + lq * 8;
            }
            __builtin_amdgcn_global_load_lds((gptr_t)gp, (lptr_t)(lds + idx * 512), 16, 0, 0);
        }
        __syncthreads();
        b16x8 af[4], bf[4];
#pragma unroll
        for (int i = 0; i < 4; ++i) {
            af[i] = *(const b16x8*)(lds + (wr * 4 + i) * 512 + l * 8);
            bf[i] = *(const b16x8*)(lds + (8 + wc * 4 + i) * 512 + l * 8);
        }
#pragma unroll
        for (int fr = 0; fr < 4; ++fr)
#pragma unroll
            for (int fc = 0; fc < 4; ++fc)
                acc[fr][fc] = __builtin_amdgcn_mfma_f32_16x16x32_bf16(af[fr], bf[fc], acc[fr][fc], 0, 0, 0);
    }

#pragma unroll
    for (int fr = 0; fr < 4; ++fr) {
#pragma unroll
        for (int r = 0; r < 4; ++r) {
            const int row = bm + wr * 64 + fr * 16 + lq * 4 + r;
            if (row >= M) continue;
#pragma unroll
            for (int fc = 0; fc < 4; ++fc) {
                const int col = bn + wc * 64 + fc * 16 + lm;
                float v = acc[fr][fc][r];
                if (BMODE == 1) v += bias[col];
                if (BMODE == 2) v += bias[row];
                if (RELU) v = fmaxf(v, 0.0f);
                size_t addr;
                if (PERM) {
                    const unsigned bb = (unsigned)col / 2000u;
                    const unsigned mm = (unsigned)col - bb * 2000u;
                    addr = ((size_t)bb * 128 + row) * KP + mm;
                } else {
                    addr = (size_t)row * ldc + col;
                }
                C[addr] = f2bf(v);
            }
        }
    }
}

// ---------------------------------------------------------------- conv GEMM, 128x128 tile, BK=32, 512 threads (8 waves)
// Xt[n][(b,e)] = inv_rs[n] * (simb @ ENCt^T).  Wave w: rows wr*64.., cols wc*32..
__global__ __launch_bounds__(512) void k_conv(
        const u16* __restrict__ simb, const u16* __restrict__ ENCt,
        u16* __restrict__ Xt, const float* __restrict__ inv_rs) {
    __shared__ u16 lds[16 * 512];           // 16 chunks x 1KB (A: 0-7, B: 8-15)
    const int tid = threadIdx.x;
    const int w = tid >> 6, l = tid & 63;   // 8 waves
    const int wr = w & 1, wc = w >> 1;      // wc in [0,4)
    const int bm = blockIdx.x * 128, bn = blockIdx.y * 128;
    const int lm = l & 15, lq = l >> 4;

    f32x4 acc[4][2] = {};

    for (int k0 = 0; k0 < KP; k0 += 32) {
        __syncthreads();
#pragma unroll
        for (int i = 0; i < 2; ++i) {
            const int idx = w * 2 + i;
            const u16* gp;
            if (idx < 8) {
                int row = bm + idx * 16 + lm;
                row = row < NN ? row : NN - 1;
                gp = simb + (size_t)row * KP + k0 + lq * 8;
            } else {
                gp = ENCt + (size_t)(bn + (idx - 8) * 16 + lm) * KP + k0 + lq * 8;
            }
            __builtin_amdgcn_global_load_lds((gptr_t)gp, (lptr_t)(lds + idx * 512), 16, 0, 0);
        }
        __syncthreads();
        b16x8 af[4], bf[2];
#pragma unroll
        for (int i = 0; i < 4; ++i) af[i] = *(const b16x8*)(lds + (wr * 4 + i) * 512 + l * 8);
#pragma unroll
        for (int j = 0; j < 2; ++j) bf[j] = *(const b16x8*)(lds + (8 + wc * 2 + j) * 512 + l * 8);
#pragma unroll
        for (int i = 0; i < 4; ++i)
#pragma unroll
            for (int j = 0; j < 2; ++j)
                acc[i][j] = __builtin_amdgcn_mfma_f32_16x16x32_bf16(af[i], bf[j], acc[i][j], 0, 0, 0);
    }

#pragma unroll
    for (int i = 0; i < 4; ++i) {
#pragma unroll
        for (int r = 0; r < 4; ++r) {
            const int row = bm + wr * 64 + i * 16 + lq * 4 + r;
            if (row >= NN) continue;
            const float rsv = inv_rs[row];
#pragma unroll
            for (int j = 0; j < 2; ++j) {
                const int col = bn + wc * 32 + j * 16 + lm;
                Xt[(size_t)row * 4096 + col] = f2bf(acc[i][j][r] * rsv);
            }
        }
    }
}

// ---------------------------------------------------------------- per-agent kernel
// grid 2048x256 = 8192 waves; wave wg: b=wg&31, ng=wg>>5 (0..255).
// Wave handles node PAIRS p = ng+256k (rows 2p, 2p+1 via half-waves, uint4 loads).
// Every wave recomputes sam(ag-1) from pin (bit-identical); one float2 out, no atomics.
// Blocks 0..31 additionally finalize agent ag-1.
__global__ __launch_bounds__(256) void k_agent(
        const u16* __restrict__ y0, const float* __restrict__ Wq1,
        const float* __restrict__ Wq2, const float* __restrict__ bq2,
        float* actions, const float2* __restrict__ pin, float2* __restrict__ pout,
        float* __restrict__ out, int ag) {
    __shared__ float sh[256];
    __shared__ float s_sam;
    const int t = threadIdx.x;
    const int lane = t & 63, wave = t >> 6;
    const int wg = blockIdx.x * 4 + wave;
    const int b = wg & 31, ng = wg >> 5;        // ng in [0,256)
    const int hl = lane & 31, half = lane >> 5;

    float act[NA];
#pragma unroll
    for (int a = 0; a < NA; ++a) act[a] = actions[b * NA + a];
    if (ag > 0) {
        const float2 p0 = pin[b * NGP + lane];
        const float2 p1 = pin[b * NGP + 64 + lane];
        const float2 p2 = pin[b * NGP + 128 + lane];
        const float2 p3 = pin[b * NGP + 192 + lane];
        float se0 = p0.x + p1.x + p2.x + p3.x;
        float sn0 = p0.y + p1.y + p2.y + p3.y;
#pragma unroll
        for (int m = 32; m > 0; m >>= 1) {
            se0 += __shfl_xor(se0, m); sn0 += __shfl_xor(sn0, m);
        }
        const float sam = fminf(fmaxf(sn0 / se0, 0.0f), 2000.0f);
        act[ag - 1] = sam * (1.0f / ACTION_NORM);
    }
    // ap slice (8 elements) and w2 slice for this half-lane
    float ap8[8] = {};
#pragma unroll
    for (int a = 0; a < NA; ++a) {
        const float4 wqa = *(const float4*)(Wq1 + (size_t)(NE + a) * NH + hl * 8);
        const float4 wqb = *(const float4*)(Wq1 + (size_t)(NE + a) * NH + hl * 8 + 4);
        ap8[0] = fmaf(act[a], wqa.x, ap8[0]); ap8[1] = fmaf(act[a], wqa.y, ap8[1]);
        ap8[2] = fmaf(act[a], wqa.z, ap8[2]); ap8[3] = fmaf(act[a], wqa.w, ap8[3]);
        ap8[4] = fmaf(act[a], wqb.x, ap8[4]); ap8[5] = fmaf(act[a], wqb.y, ap8[5]);
        ap8[6] = fmaf(act[a], wqb.z, ap8[6]); ap8[7] = fmaf(act[a], wqb.w, ap8[7]);
    }
    const float4 w2a = *(const float4*)(Wq2 + hl * 8);
    const float4 w2b = *(const float4*)(Wq2 + hl * 8 + 4);
    const float w2v[8] = {w2a.x, w2a.y, w2a.z, w2a.w, w2b.x, w2b.y, w2b.z, w2b.w};

    float se = 0.0f, sn = 0.0f;
    for (int p = ng; p < NN / 2; p += NGP) {
        const int n = 2 * p + half;
        const uint4 yv = *(const uint4*)(y0 + ((size_t)n * NB + b) * NH + hl * 8);
        const unsigned uu[4] = {yv.x, yv.y, yv.z, yv.w};
        float q = 0.0f;
#pragma unroll
        for (int j = 0; j < 4; ++j) {
            q += fmaxf(__uint_as_float(uu[j] << 16) + ap8[2 * j], 0.f) * w2v[2 * j];
            q += fmaxf(__uint_as_float(uu[j] & 0xFFFF0000u) + ap8[2 * j + 1], 0.f) * w2v[2 * j + 1];
        }
#pragma unroll
        for (int off = 16; off > 0; off >>= 1) q += __shfl_xor(q, off);
        if (hl == 0) {
            const float e = expf(fminf(q, 60.0f));
            se += e; sn += e * (float)n;
        }
    }
    se += __shfl_xor(se, 32); sn += __shfl_xor(sn, 32);
    if (lane == 0) pout[b * NGP + ng] = make_float2(se, sn);

    if (ag > 0 && blockIdx.x < NB) {
        const int bb = blockIdx.x;
        if (wave == 0) {
            const float2 p0 = pin[bb * NGP + lane];
            const float2 p1 = pin[bb * NGP + 64 + lane];
            const float2 p2 = pin[bb * NGP + 128 + lane];
            const float2 p3 = pin[bb * NGP + 192 + lane];
            float a1 = p0.x + p1.x + p2.x + p3.x;
            float a2 = p0.y + p1.y + p2.y + p3.y;
#pragma unroll
            for (int m = 32; m > 0; m >>= 1) {
                a1 += __shfl_xor(a1, m); a2 += __shfl_xor(a2, m);
            }
            if (lane == 0) s_sam = fminf(fmaxf(a2 / a1, 0.0f), 2000.0f);
        }
        __syncthreads();
        const float sam = s_sam;
        const float samn = sam * (1.0f / ACTION_NORM);
        float apt = 0.0f;
#pragma unroll
        for (int a = 0; a < NA; ++a) {
            const float av = (a == ag - 1) ? samn : actions[bb * NA + a];
            apt = fmaf(av, Wq1[(size_t)(NE + a) * NH + t], apt);
        }
        int nsel = (int)sam; if (nsel > NN - 1) nsel = NN - 1;
        const float yv = bf2f(y0[((size_t)nsel * NB + bb) * NH + t]);
        sh[t] = fmaxf(yv + apt, 0.0f) * Wq2[t];
        __syncthreads();
        for (int s = 128; s > 0; s >>= 1) {
            if (t < s) sh[t] += sh[t + s];
            __syncthreads();
        }
        if (t == 0) {
            out[bb * NA + (ag - 1)] = sh[0] + bq2[0];
            actions[bb * NA + (ag - 1)] = samn;
        }
    }
}

// ---------------------------------------------------------------- tail: finalize agent 7 + chosen
__global__ __launch_bounds__(256) void k_fin(
        const u16* __restrict__ y0, const float* __restrict__ Wq1,
        const float* __restrict__ Wq2, const float* __restrict__ bq2,
        const float* __restrict__ actions, const float2* __restrict__ pin,
        float* __restrict__ out) {
    __shared__ float sh[256];
    __shared__ float s_sam;
    const int bb = blockIdx.x, t = threadIdx.x;
    const int lane = t & 63, wave = t >> 6;
    if (wave == 0) {
        const float2 p0 = pin[bb * NGP + lane];
        const float2 p1 = pin[bb * NGP + 64 + lane];
        const float2 p2 = pin[bb * NGP + 128 + lane];
        const float2 p3 = pin[bb * NGP + 192 + lane];
        float a1 = p0.x + p1.x + p2.x + p3.x;
        float a2 = p0.y + p1.y + p2.y + p3.y;
#pragma unroll
        for (int m = 32; m > 0; m >>= 1) {
            a1 += __shfl_xor(a1, m); a2 += __shfl_xor(a2, m);
        }
        if (lane == 0) s_sam = fminf(fmaxf(a2 / a1, 0.0f), 2000.0f);
    }
    __syncthreads();
    const float sam = s_sam;
    const float samn = sam * (1.0f / ACTION_NORM);
    float apt = 0.0f;
#pragma unroll
    for (int a = 0; a < NA; ++a) {
        const float av = (a == NA - 1) ? samn : actions[bb * NA + a];
        apt = fmaf(av, Wq1[(size_t)(NE + a) * NH + t], apt);
    }
    int nsel = (int)sam; if (nsel > NN - 1) nsel = NN - 1;
    const float yv = bf2f(y0[((size_t)nsel * NB + bb) * NH + t]);
    sh[t] = fmaxf(yv + apt, 0.0f) * Wq2[t];
    __syncthreads();
    for (int s = 128; s > 0; s >>= 1) {
        if (t < s) sh[t] += sh[t + s];
        __syncthreads();
    }
    if (t == 0) out[bb * NA + (NA - 1)] = sh[0] + bq2[0];
    if (t < NA) {
        const float av = (t == NA - 1) ? samn : actions[bb * NA + t];
        out[NB * NA + bb * NA + t] = (float)(int)(av * ACTION_NORM);
    }
}

// ---------------------------------------------------------------- launch
extern "C" void kernel_launch(void* const* d_in, const int* in_sizes, int n_in,
                              void* d_out, int out_size, void* d_ws, size_t ws_size,
                              hipStream_t stream) {
    const float* state = (const float*)d_in[0];
    const float* dm    = (const float*)d_in[1];
    const float* W1    = (const float*)d_in[2];
    const float* b1    = (const float*)d_in[3];
    const float* W2    = (const float*)d_in[4];
    const float* b2    = (const float*)d_in[5];
    const float* Wq1   = (const float*)d_in[6];
    const float* bq1   = (const float*)d_in[7];
    const float* Wq2   = (const float*)d_in[8];
    const float* bq2   = (const float*)d_in[9];
    const int* fa      = (const int*)d_in[10];
    const int* fid     = (const int*)d_in[11];
    float* out = (float*)d_out;

    char* p = (char*)d_ws;
    u16* simb      = (u16*)p;      p += (size_t)NN * KP * 2;        // 8.06 MB
    float* inv_rs  = (float*)p;    p += 2048 * 4;
    unsigned* dmax_u = (unsigned*)p; p += 256;
    float* actions = (float*)p;    p += 256 * 4;
    float2* part0  = (float2*)p;   p += (size_t)NB * NGP * 8;
    float2* part1  = (float2*)p;   p += (size_t)NB * NGP * 8;
    u16* state_b   = (u16*)p;      p += (size_t)2048000 * 2;
    u16* W1t       = (u16*)p;      p += 8192 * 2;
    u16* W2t       = (u16*)p;      p += 32768 * 2;
    u16* Wq1at     = (u16*)p;      p += 32768 * 2;
    u16* h1        = (u16*)p;      p += (size_t)16384000 * 2;       // 32.8 MB
    u16* ENCt      = (u16*)p;      p += (size_t)4096 * KP * 2;      // 16.5 MB
    u16* Xt        = (u16*)p;      p += (size_t)8192000 * 2;        // 16.4 MB
    u16* y0w       = (u16*)p;      p += (size_t)16384000 * 2;       // 32.8 MB

    const int RTOT = NB * NN;  // 64000

    k_prep<<<(PREP_TOT + 255) / 256, 256, 0, stream>>>(state, W1, W2, Wq1,
                                                       state_b, W1t, W2t, Wq1at, ENCt);
    k_init<<<1, 256, 0, stream>>>(dmax_u, actions, fa, fid);
    k_max<<<1024, 256, 0, stream>>>(dm, dmax_u, NN * NN);
    k_sim<<<NN, 256, 0, stream>>>(dm, dmax_u, simb, inv_rs);

    // enc1: h1 = relu(state @ W1 + b1)  [64000,256]
    mfma_gemm<1, 1, 0><<<dim3(RTOT / 128, NH / 128), 256, 0, stream>>>(
        state_b, W1t, h1, RTOT, NH, NRD, NRD, NRD, NH, b1);
    // enc2 (transposed out, (b,e) rows): ENCt[(b,e)][m] = (W2t @ h1^T) + b2[row]
    mfma_gemm<0, 2, 1><<<dim3(1, RTOT / 128), 256, 0, stream>>>(
        W2t, h1, ENCt, NE, RTOT, NH, NH, NH, 0, b2);
    // conv: Xt[n][(b,e)] = inv_rs[n] * (simb @ ENCt^T)  [2000 x 4096], 512-thread blocks
    k_conv<<<dim3(16, 32), 512, 0, stream>>>(simb, ENCt, Xt, inv_rs);
    // y0 = Xt @ Wq1[:128] + bq1  [64000,256]  (Xt rows are (n,b), stride 128)
    mfma_gemm<0, 1, 0><<<dim3(RTOT / 128, NH / 128), 256, 0, stream>>>(
        Xt, Wq1at, y0w, RTOT, NH, NE, NE, NE, NH, bq1);

    // 8-agent loop: one kernel per agent, double-buffered partials
    for (int ag = 0; ag < NA; ++ag) {
        const float2* pin  = (ag & 1) ? part0 : part1;
        float2*       pout = (ag & 1) ? part1 : part0;
        k_agent<<<2048, 256, 0, stream>>>(y0w, Wq1, Wq2, bq2, actions,
                                          pin, pout, out, ag);
    }
    // finalize agent 7 (+ chosen); ag=7 wrote part1
    k_fin<<<NB, 256, 0, stream>>>(y0w, Wq1, Wq2, bq2, actions, part1, out);
}

// Round 8
// 293.705 us; speedup vs baseline: 1.2764x; 1.0660x over previous
//
#include <hip/hip_runtime.h>
#include <cstddef>

#define NB 32
#define NN 2000
#define NRD 32
#define NE 128
#define NH 256
#define NA 8
#define KP8 2048         // conv K padded (fp8, BK=64)
#define NGP 256          // node-pair groups per batch in k_agent
#define ACTION_NORM 2000.0f

typedef unsigned short u16;
typedef unsigned char u8;
typedef __bf16 b16x8 __attribute__((ext_vector_type(8)));
typedef float f32x4 __attribute__((ext_vector_type(4)));
typedef const __attribute__((address_space(1))) unsigned int* gptr_t;
typedef __attribute__((address_space(3))) unsigned int* lptr_t;

__device__ inline u16 f2bf(float x) {
    unsigned u = __float_as_uint(x);
    u += 0x7FFFu + ((u >> 16) & 1u);
    return (u16)(u >> 16);
}
__device__ inline float bf2f(u16 h) { return __uint_as_float((unsigned)h << 16); }
__device__ inline u8 f2fp8(float x) {
    return (u8)(__builtin_amdgcn_cvt_pk_fp8_f32(x, x, 0, false) & 0xFF);
}
__device__ inline u16 f2fp8x2(float a, float b) {
    return (u16)(__builtin_amdgcn_cvt_pk_fp8_f32(a, b, 0, false) & 0xFFFF);
}

// ---------------------------------------------------------------- init: dmax reset + actions
__global__ __launch_bounds__(256) void k_init(unsigned* dmax_u, float* actions,
                                              const int* __restrict__ fa,
                                              const int* __restrict__ fid) {
    const int t = threadIdx.x;            // t = b*8 + a
    if (t == 0) *dmax_u = 0u;
    const int b = t >> 3, a = t & 7;
    float v = -1.0f;
    for (int j = 0; j < 3; ++j)
        if (fid[j] == a) v = (float)fa[j * NB + b] / ACTION_NORM;
    actions[t] = v;
}

// ---------------------------------------------------------------- global max of dm
__global__ __launch_bounds__(256) void k_max(const float* __restrict__ dm,
                                             unsigned* dmax_u, int n) {
    __shared__ float sh[256];
    float m = 0.0f;
    for (int i = blockIdx.x * blockDim.x + threadIdx.x; i < n; i += gridDim.x * blockDim.x)
        m = fmaxf(m, dm[i]);
    sh[threadIdx.x] = m; __syncthreads();
    for (int s = 128; s > 0; s >>= 1) {
        if (threadIdx.x < s) sh[threadIdx.x] = fmaxf(sh[threadIdx.x], sh[threadIdx.x + s]);
        __syncthreads();
    }
    if (threadIdx.x == 0) atomicMax(dmax_u, __float_as_uint(sh[0]));
}

// ---------------------------------------------------------------- sim rows -> fp8 pairs (K padded), inv rowsum (fp32)
__global__ __launch_bounds__(256) void k_sim(const float* __restrict__ dm,
                                             const unsigned* __restrict__ dmax_u,
                                             u8* __restrict__ simb,
                                             float* __restrict__ inv_rs) {
    __shared__ float sh[256];
    const int n = blockIdx.x;
    const float inv = 1.0f / __uint_as_float(*dmax_u);
    float s = 0.0f;
    for (int m = threadIdx.x * 2; m < KP8; m += 512) {
        float e0 = 0.0f, e1 = 0.0f;
        if (m < NN)     { e0 = expf(-dm[(size_t)n * NN + m] * inv);     s += e0; }
        if (m + 1 < NN) { e1 = expf(-dm[(size_t)n * NN + m + 1] * inv); s += e1; }
        *(u16*)(simb + (size_t)n * KP8 + m) = f2fp8x2(e0, e1);
    }
    sh[threadIdx.x] = s; __syncthreads();
    for (int st = 128; st > 0; st >>= 1) {
        if (threadIdx.x < st) sh[threadIdx.x] += sh[threadIdx.x + st];
        __syncthreads();
    }
    if (threadIdx.x == 0) inv_rs[n] = 1.0f / sh[0];
}

// ---------------------------------------------------------------- prep: convert state, transpose weights, zero ENC fp8 pad
#define PREP_STATE (64000 * 32)
#define PREP_W1T   (256 * 32)
#define PREP_W2T   (128 * 256)
#define PREP_WQ1T  (256 * 128)
#define PREP_PAD   (4096 * 48)
#define PREP_TOT   (PREP_STATE + PREP_W1T + PREP_W2T + PREP_WQ1T + PREP_PAD)
__global__ __launch_bounds__(256) void k_prep(const float* __restrict__ state,
                                              const float* __restrict__ W1,
                                              const float* __restrict__ W2,
                                              const float* __restrict__ Wq1,
                                              u16* __restrict__ state_b, u16* __restrict__ W1t,
                                              u16* __restrict__ W2t, u16* __restrict__ Wq1at,
                                              u8* __restrict__ encb) {
    int i = blockIdx.x * 256 + threadIdx.x;
    if (i < PREP_STATE) { state_b[i] = f2bf(state[i]); return; }
    i -= PREP_STATE;
    if (i < PREP_W1T) { int h = i >> 5, k = i & 31; W1t[i] = f2bf(W1[k * NH + h]); return; }
    i -= PREP_W1T;
    if (i < PREP_W2T) { int e = i >> 8, h = i & 255; W2t[i] = f2bf(W2[h * NE + e]); return; }
    i -= PREP_W2T;
    if (i < PREP_WQ1T) { int hq = i >> 7, e = i & 127; Wq1at[i] = f2bf(Wq1[e * NH + hq]); return; }
    i -= PREP_WQ1T;
    if (i < PREP_PAD) { int eb = i / 48, mm = NN + (i % 48); encb[(size_t)eb * KP8 + mm] = 0; }
}

// ---------------------------------------------------------------- bf16 NT MFMA GEMM, 128x128 tile, BK=32, 256 threads
// C = A[M][K] * (Bt[N][K])^T ; out bf16. BMODE: 0 none, 1 bias[col].
template<int RELU, int BMODE>
__global__ __launch_bounds__(256) void mfma_gemm(
        const u16* __restrict__ A, const u16* __restrict__ Bt, u16* __restrict__ C,
        int M, int N, int K, int lda, int ldb, int ldc,
        const float* __restrict__ bias) {
    __shared__ u16 lds[16 * 512];           // 16 chunks x 1KB (A: 0-7, B: 8-15)
    const int tid = threadIdx.x;
    const int w = tid >> 6, l = tid & 63;
    const int wr = w & 1, wc = w >> 1;
    const int bm = blockIdx.x * 128, bn = blockIdx.y * 128;
    const int lm = l & 15, lq = l >> 4;

    f32x4 acc[4][4] = {};

    for (int k0 = 0; k0 < K; k0 += 32) {
        __syncthreads();
#pragma unroll
        for (int i = 0; i < 4; ++i) {
            const int idx = w * 4 + i;
            const u16* gp;
            if (idx < 8) {
                int row = bm + idx * 16 + lm;
                row = row < M ? row : M - 1;
                gp = A + (size_t)row * lda + k0 + lq * 8;
            } else {
                const int col = bn + (idx - 8) * 16 + lm;
                gp = Bt + (size_t)col * ldb + k0 + lq * 8;
            }
            __builtin_amdgcn_global_load_lds((gptr_t)gp, (lptr_t)(lds + idx * 512), 16, 0, 0);
        }
        __syncthreads();
        b16x8 af[4], bf[4];
#pragma unroll
        for (int i = 0; i < 4; ++i) {
            af[i] = *(const b16x8*)(lds + (wr * 4 + i) * 512 + l * 8);
            bf[i] = *(const b16x8*)(lds + (8 + wc * 4 + i) * 512 + l * 8);
        }
#pragma unroll
        for (int fr = 0; fr < 4; ++fr)
#pragma unroll
            for (int fc = 0; fc < 4; ++fc)
                acc[fr][fc] = __builtin_amdgcn_mfma_f32_16x16x32_bf16(af[fr], bf[fc], acc[fr][fc], 0, 0, 0);
    }

#pragma unroll
    for (int fr = 0; fr < 4; ++fr) {
#pragma unroll
        for (int r = 0; r < 4; ++r) {
            const int row = bm + wr * 64 + fr * 16 + lq * 4 + r;
            if (row >= M) continue;
#pragma unroll
            for (int fc = 0; fc < 4; ++fc) {
                const int col = bn + wc * 64 + fc * 16 + lm;
                float v = acc[fr][fc][r];
                if (BMODE == 1) v += bias[col];
                if (RELU) v = fmaxf(v, 0.0f);
                C[(size_t)row * ldc + col] = f2bf(v);
            }
        }
    }
}

// ---------------------------------------------------------------- enc2: 512 threads, bf16 in, fp8 PERM out
// ENCf8[(b*128 + row)][m] = fp8(W2t @ h1^T + b2[row]), col=(b*2000+m)
__global__ __launch_bounds__(512) void k_enc2(
        const u16* __restrict__ W2t, const u16* __restrict__ h1,
        u8* __restrict__ encb, const float* __restrict__ b2) {
    __shared__ u16 lds[16 * 512];
    const int tid = threadIdx.x;
    const int w = tid >> 6, l = tid & 63;   // 8 waves
    const int wr = w & 1, wc = w >> 1;      // wc in [0,4)
    const int bn = blockIdx.y * 128;
    const int lm = l & 15, lq = l >> 4;

    f32x4 acc[4][2] = {};

    for (int k0 = 0; k0 < NH; k0 += 32) {
        __syncthreads();
#pragma unroll
        for (int i = 0; i < 2; ++i) {
            const int idx = w * 2 + i;
            const u16* gp;
            if (idx < 8) {
                gp = W2t + (size_t)(idx * 16 + lm) * NH + k0 + lq * 8;
            } else {
                gp = h1 + (size_t)(bn + (idx - 8) * 16 + lm) * NH + k0 + lq * 8;
            }
            __builtin_amdgcn_global_load_lds((gptr_t)gp, (lptr_t)(lds + idx * 512), 16, 0, 0);
        }
        __syncthreads();
        b16x8 af[4], bf[2];
#pragma unroll
        for (int i = 0; i < 4; ++i) af[i] = *(const b16x8*)(lds + (wr * 4 + i) * 512 + l * 8);
#pragma unroll
        for (int j = 0; j < 2; ++j) bf[j] = *(const b16x8*)(lds + (8 + wc * 2 + j) * 512 + l * 8);
#pragma unroll
        for (int i = 0; i < 4; ++i)
#pragma unroll
            for (int j = 0; j < 2; ++j)
                acc[i][j] = __builtin_amdgcn_mfma_f32_16x16x32_bf16(af[i], bf[j], acc[i][j], 0, 0, 0);
    }

#pragma unroll
    for (int i = 0; i < 4; ++i) {
#pragma unroll
        for (int r = 0; r < 4; ++r) {
            const int row = wr * 64 + i * 16 + lq * 4 + r;   // 0..127
            const float bias = b2[row];
#pragma unroll
            for (int j = 0; j < 2; ++j) {
                const int col = bn + wc * 32 + j * 16 + lm;
                const unsigned bb = (unsigned)col / 2000u;
                const unsigned mm = (unsigned)col - bb * 2000u;
                encb[((size_t)bb * 128 + row) * KP8 + mm] = f2fp8(acc[i][j][r] + bias);
            }
        }
    }
}

// ---------------------------------------------------------------- conv GEMM fp8, 128x128 tile, BK=64, 512 threads
// Xt[n][(b,e)] = inv_rs[n] * (simb8 @ encb8^T), bf16 out.
// LDS chunk = 16 rows x 64 fp8 (1KB), staged lane l -> (row l&15, k-window (l>>4)*16B).
// Fragment (lm,lq,s): addr = chunk*1024 + (s*2+(lq>>1))*256 + lm*16 + (lq&1)*8  (8B, b64)
__global__ __launch_bounds__(512) void k_conv(
        const u8* __restrict__ simb, const u8* __restrict__ encb,
        u16* __restrict__ Xt, const float* __restrict__ inv_rs) {
    __shared__ u8 lds[16 * 1024];           // 16 chunks x 1KB (A: 0-7, B: 8-15)
    const int tid = threadIdx.x;
    const int w = tid >> 6, l = tid & 63;   // 8 waves
    const int wr = w & 1, wc = w >> 1;      // wc in [0,4)
    const int bm = blockIdx.x * 128, bn = blockIdx.y * 128;
    const int lm = l & 15, lq = l >> 4;

    f32x4 acc[4][2] = {};

    for (int k0 = 0; k0 < KP8; k0 += 64) {
        __syncthreads();
#pragma unroll
        for (int i = 0; i < 2; ++i) {
            const int idx = w * 2 + i;
            const u8* gp;
            if (idx < 8) {
                int row = bm + idx * 16 + lm;
                row = row < NN ? row : NN - 1;
                gp = simb + (size_t)row * KP8 + k0 + lq * 16;
            } else {
                gp = encb + (size_t)(bn + (idx - 8) * 16 + lm) * KP8 + k0 + lq * 16;
            }
            __builtin_amdgcn_global_load_lds((gptr_t)gp, (lptr_t)(lds + idx * 1024), 16, 0, 0);
        }
        __syncthreads();
        const int fo = ((lq >> 1) << 8) + lm * 16 + (lq & 1) * 8;
        long af[4][2], bf[2][2];
#pragma unroll
        for (int i = 0; i < 4; ++i) {
            af[i][0] = *(const long*)(lds + (wr * 4 + i) * 1024 + fo);
            af[i][1] = *(const long*)(lds + (wr * 4 + i) * 1024 + 512 + fo);
        }
#pragma unroll
        for (int j = 0; j < 2; ++j) {
            bf[j][0] = *(const long*)(lds + (8 + wc * 2 + j) * 1024 + fo);
            bf[j][1] = *(const long*)(lds + (8 + wc * 2 + j) * 1024 + 512 + fo);
        }
#pragma unroll
        for (int i = 0; i < 4; ++i)
#pragma unroll
            for (int j = 0; j < 2; ++j) {
                acc[i][j] = __builtin_amdgcn_mfma_f32_16x16x32_fp8_fp8(af[i][0], bf[j][0], acc[i][j], 0, 0, 0);
                acc[i][j] = __builtin_amdgcn_mfma_f32_16x16x32_fp8_fp8(af[i][1], bf[j][1], acc[i][j], 0, 0, 0);
            }
    }

#pragma unroll
    for (int i = 0; i < 4; ++i) {
#pragma unroll
        for (int r = 0; r < 4; ++r) {
            const int row = bm + wr * 64 + i * 16 + lq * 4 + r;
            if (row >= NN) continue;
            const float rsv = inv_rs[row];
#pragma unroll
            for (int j = 0; j < 2; ++j) {
                const int col = bn + wc * 32 + j * 16 + lm;
                Xt[(size_t)row * 4096 + col] = f2bf(acc[i][j][r] * rsv);
            }
        }
    }
}

// ---------------------------------------------------------------- per-agent kernel
// grid 2048x256 = 8192 waves; wave wg: b=wg&31, ng=wg>>5 (0..255).
// Wave handles node PAIRS p = ng+256k (rows 2p, 2p+1 via half-waves, uint4 loads).
// Every wave recomputes sam(ag-1) from pin (bit-identical); one float2 out, no atomics.
// Blocks 0..31 additionally finalize agent ag-1.
__global__ __launch_bounds__(256) void k_agent(
        const u16* __restrict__ y0, const float* __restrict__ Wq1,
        const float* __restrict__ Wq2, const float* __restrict__ bq2,
        float* actions, const float2* __restrict__ pin, float2* __restrict__ pout,
        float* __restrict__ out, int ag) {
    __shared__ float sh[256];
    __shared__ float s_sam;
    const int t = threadIdx.x;
    const int lane = t & 63, wave = t >> 6;
    const int wg = blockIdx.x * 4 + wave;
    const int b = wg & 31, ng = wg >> 5;        // ng in [0,256)
    const int hl = lane & 31, half = lane >> 5;

    float act[NA];
#pragma unroll
    for (int a = 0; a < NA; ++a) act[a] = actions[b * NA + a];
    if (ag > 0) {
        const float2 p0 = pin[b * NGP + lane];
        const float2 p1 = pin[b * NGP + 64 + lane];
        const float2 p2 = pin[b * NGP + 128 + lane];
        const float2 p3 = pin[b * NGP + 192 + lane];
        float se0 = p0.x + p1.x + p2.x + p3.x;
        float sn0 = p0.y + p1.y + p2.y + p3.y;
#pragma unroll
        for (int m = 32; m > 0; m >>= 1) {
            se0 += __shfl_xor(se0, m); sn0 += __shfl_xor(sn0, m);
        }
        const float sam = fminf(fmaxf(sn0 / se0, 0.0f), 2000.0f);
        act[ag - 1] = sam * (1.0f / ACTION_NORM);
    }
    // ap slice (8 elements) and w2 slice for this half-lane
    float ap8[8] = {};
#pragma unroll
    for (int a = 0; a < NA; ++a) {
        const float4 wqa = *(const float4*)(Wq1 + (size_t)(NE + a) * NH + hl * 8);
        const float4 wqb = *(const float4*)(Wq1 + (size_t)(NE + a) * NH + hl * 8 + 4);
        ap8[0] = fmaf(act[a], wqa.x, ap8[0]); ap8[1] = fmaf(act[a], wqa.y, ap8[1]);
        ap8[2] = fmaf(act[a], wqa.z, ap8[2]); ap8[3] = fmaf(act[a], wqa.w, ap8[3]);
        ap8[4] = fmaf(act[a], wqb.x, ap8[4]); ap8[5] = fmaf(act[a], wqb.y, ap8[5]);
        ap8[6] = fmaf(act[a], wqb.z, ap8[6]); ap8[7] = fmaf(act[a], wqb.w, ap8[7]);
    }
    const float4 w2a = *(const float4*)(Wq2 + hl * 8);
    const float4 w2b = *(const float4*)(Wq2 + hl * 8 + 4);
    const float w2v[8] = {w2a.x, w2a.y, w2a.z, w2a.w, w2b.x, w2b.y, w2b.z, w2b.w};

    float se = 0.0f, sn = 0.0f;
    for (int p = ng; p < NN / 2; p += NGP) {
        const int n = 2 * p + half;
        const uint4 yv = *(const uint4*)(y0 + ((size_t)n * NB + b) * NH + hl * 8);
        const unsigned uu[4] = {yv.x, yv.y, yv.z, yv.w};
        float q = 0.0f;
#pragma unroll
        for (int j = 0; j < 4; ++j) {
            q += fmaxf(__uint_as_float(uu[j] << 16) + ap8[2 * j], 0.f) * w2v[2 * j];
            q += fmaxf(__uint_as_float(uu[j] & 0xFFFF0000u) + ap8[2 * j + 1], 0.f) * w2v[2 * j + 1];
        }
#pragma unroll
        for (int off = 16; off > 0; off >>= 1) q += __shfl_xor(q, off);
        if (hl == 0) {
            const float e = expf(fminf(q, 60.0f));
            se += e; sn += e * (float)n;
        }
    }
    se += __shfl_xor(se, 32); sn += __shfl_xor(sn, 32);
    if (lane == 0) pout[b * NGP + ng] = make_float2(se, sn);

    if (ag > 0 && blockIdx.x < NB) {
        const int bb = blockIdx.x;
        if (wave == 0) {
            const float2 p0 = pin[bb * NGP + lane];
            const float2 p1 = pin[bb * NGP + 64 + lane];
            const float2 p2 = pin[bb * NGP + 128 + lane];
            const float2 p3 = pin[bb * NGP + 192 + lane];
            float a1 = p0.x + p1.x + p2.x + p3.x;
            float a2 = p0.y + p1.y + p2.y + p3.y;
#pragma unroll
            for (int m = 32; m > 0; m >>= 1) {
                a1 += __shfl_xor(a1, m); a2 += __shfl_xor(a2, m);
            }
            if (lane == 0) s_sam = fminf(fmaxf(a2 / a1, 0.0f), 2000.0f);
        }
        __syncthreads();
        const float sam = s_sam;
        const float samn = sam * (1.0f / ACTION_NORM);
        float apt = 0.0f;
#pragma unroll
        for (int a = 0; a < NA; ++a) {
            const float av = (a == ag - 1) ? samn : actions[bb * NA + a];
            apt = fmaf(av, Wq1[(size_t)(NE + a) * NH + t], apt);
        }
        int nsel = (int)sam; if (nsel > NN - 1) nsel = NN - 1;
        const float yv = bf2f(y0[((size_t)nsel * NB + bb) * NH + t]);
        sh[t] = fmaxf(yv + apt, 0.0f) * Wq2[t];
        __syncthreads();
        for (int s = 128; s > 0; s >>= 1) {
            if (t < s) sh[t] += sh[t + s];
            __syncthreads();
        }
        if (t == 0) {
            out[bb * NA + (ag - 1)] = sh[0] + bq2[0];
            actions[bb * NA + (ag - 1)] = samn;
        }
    }
}

// ---------------------------------------------------------------- tail: finalize agent 7 + chosen
__global__ __launch_bounds__(256) void k_fin(
        const u16* __restrict__ y0, const float* __restrict__ Wq1,
        const float* __restrict__ Wq2, const float* __restrict__ bq2,
        const float* __restrict__ actions, const float2* __restrict__ pin,
        float* __restrict__ out) {
    __shared__ float sh[256];
    __shared__ float s_sam;
    const int bb = blockIdx.x, t = threadIdx.x;
    const int lane = t & 63, wave = t >> 6;
    if (wave == 0) {
        const float2 p0 = pin[bb * NGP + lane];
        const float2 p1 = pin[bb * NGP + 64 + lane];
        const float2 p2 = pin[bb * NGP + 128 + lane];
        const float2 p3 = pin[bb * NGP + 192 + lane];
        float a1 = p0.x + p1.x + p2.x + p3.x;
        float a2 = p0.y + p1.y + p2.y + p3.y;
#pragma unroll
        for (int m = 32; m > 0; m >>= 1) {
            a1 += __shfl_xor(a1, m); a2 += __shfl_xor(a2, m);
        }
        if (lane == 0) s_sam = fminf(fmaxf(a2 / a1, 0.0f), 2000.0f);
    }
    __syncthreads();
    const float sam = s_sam;
    const float samn = sam * (1.0f / ACTION_NORM);
    float apt = 0.0f;
#pragma unroll
    for (int a = 0; a < NA; ++a) {
        const float av = (a == NA - 1) ? samn : actions[bb * NA + a];
        apt = fmaf(av, Wq1[(size_t)(NE + a) * NH + t], apt);
    }
    int nsel = (int)sam; if (nsel > NN - 1) nsel = NN - 1;
    const float yv = bf2f(y0[((size_t)nsel * NB + bb) * NH + t]);
    sh[t] = fmaxf(yv + apt, 0.0f) * Wq2[t];
    __syncthreads();
    for (int s = 128; s > 0; s >>= 1) {
        if (t < s) sh[t] += sh[t + s];
        __syncthreads();
    }
    if (t == 0) out[bb * NA + (NA - 1)] = sh[0] + bq2[0];
    if (t < NA) {
        const float av = (t == NA - 1) ? samn : actions[bb * NA + t];
        out[NB * NA + bb * NA + t] = (float)(int)(av * ACTION_NORM);
    }
}

// ---------------------------------------------------------------- launch
extern "C" void kernel_launch(void* const* d_in, const int* in_sizes, int n_in,
                              void* d_out, int out_size, void* d_ws, size_t ws_size,
                              hipStream_t stream) {
    const float* state = (const float*)d_in[0];
    const float* dm    = (const float*)d_in[1];
    const float* W1    = (const float*)d_in[2];
    const float* b1    = (const float*)d_in[3];
    const float* W2    = (const float*)d_in[4];
    const float* b2    = (const float*)d_in[5];
    const float* Wq1   = (const float*)d_in[6];
    const float* bq1   = (const float*)d_in[7];
    const float* Wq2   = (const float*)d_in[8];
    const float* bq2   = (const float*)d_in[9];
    const int* fa      = (const int*)d_in[10];
    const int* fid     = (const int*)d_in[11];
    float* out = (float*)d_out;

    char* p = (char*)d_ws;
    u8* simb       = (u8*)p;       p += (size_t)NN * KP8;           // 4.10 MB
    u8* encb       = (u8*)p;       p += (size_t)4096 * KP8;         // 8.39 MB
    float* inv_rs  = (float*)p;    p += 2048 * 4;
    unsigned* dmax_u = (unsigned*)p; p += 256;
    float* actions = (float*)p;    p += 256 * 4;
    float2* part0  = (float2*)p;   p += (size_t)NB * NGP * 8;
    float2* part1  = (float2*)p;   p += (size_t)NB * NGP * 8;
    u16* state_b   = (u16*)p;      p += (size_t)2048000 * 2;
    u16* W1t       = (u16*)p;      p += 8192 * 2;
    u16* W2t       = (u16*)p;      p += 32768 * 2;
    u16* Wq1at     = (u16*)p;      p += 32768 * 2;
    u16* h1        = (u16*)p;      p += (size_t)16384000 * 2;       // 32.8 MB
    u16* Xt        = (u16*)p;      p += (size_t)8192000 * 2;        // 16.4 MB
    u16* y0w       = (u16*)p;      p += (size_t)16384000 * 2;       // 32.8 MB

    const int RTOT = NB * NN;  // 64000

    k_prep<<<(PREP_TOT + 255) / 256, 256, 0, stream>>>(state, W1, W2, Wq1,
                                                       state_b, W1t, W2t, Wq1at, encb);
    k_init<<<1, 256, 0, stream>>>(dmax_u, actions, fa, fid);
    k_max<<<1024, 256, 0, stream>>>(dm, dmax_u, NN * NN);
    k_sim<<<NN, 256, 0, stream>>>(dm, dmax_u, simb, inv_rs);

    // enc1: h1 = relu(state @ W1 + b1)  [64000,256]
    mfma_gemm<1, 1><<<dim3(RTOT / 128, NH / 128), 256, 0, stream>>>(
        state_b, W1t, h1, RTOT, NH, NRD, NRD, NRD, NH, b1);
    // enc2 (fp8 out, (b,e) rows): encb[(b*128+e)][m] = fp8(W2t @ h1^T + b2)
    k_enc2<<<dim3(1, RTOT / 128), 512, 0, stream>>>(W2t, h1, encb, b2);
    // conv (fp8): Xt[n][(b,e)] = inv_rs[n] * (simb @ encb^T)  [2000 x 4096]
    k_conv<<<dim3(16, 32), 512, 0, stream>>>(simb, encb, Xt, inv_rs);
    // y0 = Xt @ Wq1[:128] + bq1  [64000,256]
    mfma_gemm<0, 1><<<dim3(RTOT / 128, NH / 128), 256, 0, stream>>>(
        Xt, Wq1at, y0w, RTOT, NH, NE, NE, NE, NH, bq1);

    // 8-agent loop: one kernel per agent, double-buffered partials
    for (int ag = 0; ag < NA; ++ag) {
        const float2* pin  = (ag & 1) ? part0 : part1;
        float2*       pout = (ag & 1) ? part1 : part0;
        k_agent<<<2048, 256, 0, stream>>>(y0w, Wq1, Wq2, bq2, actions,
                                          pin, pout, out, ag);
    }
    // finalize agent 7 (+ chosen); ag=7 wrote part1
    k_fin<<<NB, 256, 0, stream>>>(y0w, Wq1, Wq2, bq2, actions, part1, out);
}

// Round 9
// 288.800 us; speedup vs baseline: 1.2981x; 1.0170x over previous
//
#include <hip/hip_runtime.h>
#include <cstddef>

#define NB 32
#define NN 2000
#define NRD 32
#define NE 128
#define NH 256
#define NA 8
#define KP8 2048         // conv K padded (fp8, BK=64)
#define NGP 128          // node-quad groups per batch in k_agent
#define ACTION_NORM 2000.0f

typedef unsigned short u16;
typedef unsigned char u8;
typedef __bf16 b16x8 __attribute__((ext_vector_type(8)));
typedef float f32x4 __attribute__((ext_vector_type(4)));
typedef const __attribute__((address_space(1))) unsigned int* gptr_t;
typedef __attribute__((address_space(3))) unsigned int* lptr_t;

__device__ inline u16 f2bf(float x) {
    unsigned u = __float_as_uint(x);
    u += 0x7FFFu + ((u >> 16) & 1u);
    return (u16)(u >> 16);
}
__device__ inline float bf2f(u16 h) { return __uint_as_float((unsigned)h << 16); }
__device__ inline u8 f2fp8(float x) {
    return (u8)(__builtin_amdgcn_cvt_pk_fp8_f32(x, x, 0, false) & 0xFF);
}
__device__ inline u16 f2fp8x2(float a, float b) {
    return (u16)(__builtin_amdgcn_cvt_pk_fp8_f32(a, b, 0, false) & 0xFFFF);
}

// ---------------------------------------------------------------- front: prep + dm partial max + actions init
#define PREP_STATE (64000 * 32)
#define PREP_W1T   (256 * 32)
#define PREP_W2T   (128 * 256)
#define PREP_WQ1T  (256 * 128)
#define PREP_PAD   (4096 * 48)
#define PREP_TOT   (PREP_STATE + PREP_W1T + PREP_W2T + PREP_WQ1T + PREP_PAD)
#define PREP_BLOCKS (PREP_TOT / 256)       // 9056
#define MAX_BLOCKS 1024
__global__ __launch_bounds__(256) void k_front(
        const float* __restrict__ state, const float* __restrict__ W1,
        const float* __restrict__ W2, const float* __restrict__ Wq1,
        const float* __restrict__ dm, const int* __restrict__ fa,
        const int* __restrict__ fid,
        u16* __restrict__ state_b, u16* __restrict__ W1t,
        u16* __restrict__ W2t, u16* __restrict__ Wq1at,
        u8* __restrict__ encb, float* __restrict__ pmax,
        float* __restrict__ actions) {
    __shared__ float sh[256];
    const int blk = blockIdx.x, t = threadIdx.x;
    if (blk < PREP_BLOCKS) {
        int i = blk * 256 + t;
        if (i < PREP_STATE) { state_b[i] = f2bf(state[i]); return; }
        i -= PREP_STATE;
        if (i < PREP_W1T) { int h = i >> 5, k = i & 31; W1t[i] = f2bf(W1[k * NH + h]); return; }
        i -= PREP_W1T;
        if (i < PREP_W2T) { int e = i >> 8, h = i & 255; W2t[i] = f2bf(W2[h * NE + e]); return; }
        i -= PREP_W2T;
        if (i < PREP_WQ1T) { int hq = i >> 7, e = i & 127; Wq1at[i] = f2bf(Wq1[e * NH + hq]); return; }
        i -= PREP_WQ1T;
        if (i < PREP_PAD) { int eb = i / 48, mm = NN + (i % 48); encb[(size_t)eb * KP8 + mm] = 0; }
        return;
    }
    if (blk < PREP_BLOCKS + MAX_BLOCKS) {
        const int bid = blk - PREP_BLOCKS;
        float m = 0.0f;
        for (size_t i = (size_t)bid * 256 + t; i < (size_t)NN * NN; i += (size_t)MAX_BLOCKS * 256)
            m = fmaxf(m, dm[i]);
        sh[t] = m; __syncthreads();
        for (int s = 128; s > 0; s >>= 1) {
            if (t < s) sh[t] = fmaxf(sh[t], sh[t + s]);
            __syncthreads();
        }
        if (t == 0) pmax[bid] = sh[0];
        return;
    }
    // init actions (t = b*8 + a)
    const int b = t >> 3, a = t & 7;
    float v = -1.0f;
    for (int j = 0; j < 3; ++j)
        if (fid[j] == a) v = (float)fa[j * NB + b] / ACTION_NORM;
    actions[t] = v;
}

// ---------------------------------------------------------------- merged: enc1 GEMM (blocks 0..999) + sim (blocks 1000..2999)
// enc1: h1 = relu(state_b @ W1t^T + b1)  [64000,256], K=32
// sim: simb[n][m] = fp8(exp(-dm/dmax)), inv_rs[n]; dmax from pmax reduce
__global__ __launch_bounds__(256) void k_gemm1s(
        const u16* __restrict__ A, const u16* __restrict__ Bt, u16* __restrict__ C,
        const float* __restrict__ bias,
        const float* __restrict__ dm, const float* __restrict__ pmax,
        u8* __restrict__ simb, float* __restrict__ inv_rs) {
    __shared__ u16 lds[16 * 512];
    const int blk = blockIdx.x, tid = threadIdx.x;

    if (blk >= 1000) {
        // ---------------- sim part
        float* shf = (float*)lds;
        const int n = blk - 1000, t = tid;
        float m = fmaxf(fmaxf(pmax[t], pmax[t + 256]), fmaxf(pmax[t + 512], pmax[t + 768]));
        shf[t] = m; __syncthreads();
        for (int s = 128; s > 0; s >>= 1) {
            if (t < s) shf[t] = fmaxf(shf[t], shf[t + s]);
            __syncthreads();
        }
        const float inv = 1.0f / shf[0];
        __syncthreads();
        float s = 0.0f;
        for (int mm = t * 2; mm < KP8; mm += 512) {
            float e0 = 0.0f, e1 = 0.0f;
            if (mm < NN)     { e0 = expf(-dm[(size_t)n * NN + mm] * inv);     s += e0; }
            if (mm + 1 < NN) { e1 = expf(-dm[(size_t)n * NN + mm + 1] * inv); s += e1; }
            *(u16*)(simb + (size_t)n * KP8 + mm) = f2fp8x2(e0, e1);
        }
        shf[t] = s; __syncthreads();
        for (int st = 128; st > 0; st >>= 1) {
            if (t < st) shf[t] += shf[t + st];
            __syncthreads();
        }
        if (t == 0) inv_rs[n] = 1.0f / shf[0];
        return;
    }

    // ---------------- enc1 GEMM part (flattened (500,2) grid)
    const int w = tid >> 6, l = tid & 63;
    const int wr = w & 1, wc = w >> 1;
    const int bm = (blk >> 1) * 128, bn = (blk & 1) * 128;
    const int lm = l & 15, lq = l >> 4;

    f32x4 acc[4][4] = {};
    {
        __syncthreads();
#pragma unroll
        for (int i = 0; i < 4; ++i) {
            const int idx = w * 4 + i;
            const u16* gp;
            if (idx < 8) {
                gp = A + (size_t)(bm + idx * 16 + lm) * NRD + lq * 8;
            } else {
                gp = Bt + (size_t)(bn + (idx - 8) * 16 + lm) * NRD + lq * 8;
            }
            __builtin_amdgcn_global_load_lds((gptr_t)gp, (lptr_t)(lds + idx * 512), 16, 0, 0);
        }
        __syncthreads();
        b16x8 af[4], bf[4];
#pragma unroll
        for (int i = 0; i < 4; ++i) {
            af[i] = *(const b16x8*)(lds + (wr * 4 + i) * 512 + l * 8);
            bf[i] = *(const b16x8*)(lds + (8 + wc * 4 + i) * 512 + l * 8);
        }
#pragma unroll
        for (int fr = 0; fr < 4; ++fr)
#pragma unroll
            for (int fc = 0; fc < 4; ++fc)
                acc[fr][fc] = __builtin_amdgcn_mfma_f32_16x16x32_bf16(af[fr], bf[fc], acc[fr][fc], 0, 0, 0);
    }
#pragma unroll
    for (int fr = 0; fr < 4; ++fr) {
#pragma unroll
        for (int r = 0; r < 4; ++r) {
            const int row = bm + wr * 64 + fr * 16 + lq * 4 + r;
#pragma unroll
            for (int fc = 0; fc < 4; ++fc) {
                const int col = bn + wc * 64 + fc * 16 + lm;
                const float v = fmaxf(acc[fr][fc][r] + bias[col], 0.0f);
                C[(size_t)row * NH + col] = f2bf(v);
            }
        }
    }
}

// ---------------------------------------------------------------- enc2: 512 threads, bf16 in, fp8 PERM out
// encb[(b*128 + row)][m] = fp8(W2t @ h1^T + b2[row]), col=(b*2000+m)
__global__ __launch_bounds__(512) void k_enc2(
        const u16* __restrict__ W2t, const u16* __restrict__ h1,
        u8* __restrict__ encb, const float* __restrict__ b2) {
    __shared__ u16 lds[16 * 512];
    const int tid = threadIdx.x;
    const int w = tid >> 6, l = tid & 63;   // 8 waves
    const int wr = w & 1, wc = w >> 1;      // wc in [0,4)
    const int bn = blockIdx.y * 128;
    const int lm = l & 15, lq = l >> 4;

    f32x4 acc[4][2] = {};

    for (int k0 = 0; k0 < NH; k0 += 32) {
        __syncthreads();
#pragma unroll
        for (int i = 0; i < 2; ++i) {
            const int idx = w * 2 + i;
            const u16* gp;
            if (idx < 8) {
                gp = W2t + (size_t)(idx * 16 + lm) * NH + k0 + lq * 8;
            } else {
                gp = h1 + (size_t)(bn + (idx - 8) * 16 + lm) * NH + k0 + lq * 8;
            }
            __builtin_amdgcn_global_load_lds((gptr_t)gp, (lptr_t)(lds + idx * 512), 16, 0, 0);
        }
        __syncthreads();
        b16x8 af[4], bf[2];
#pragma unroll
        for (int i = 0; i < 4; ++i) af[i] = *(const b16x8*)(lds + (wr * 4 + i) * 512 + l * 8);
#pragma unroll
        for (int j = 0; j < 2; ++j) bf[j] = *(const b16x8*)(lds + (8 + wc * 2 + j) * 512 + l * 8);
#pragma unroll
        for (int i = 0; i < 4; ++i)
#pragma unroll
            for (int j = 0; j < 2; ++j)
                acc[i][j] = __builtin_amdgcn_mfma_f32_16x16x32_bf16(af[i], bf[j], acc[i][j], 0, 0, 0);
    }

#pragma unroll
    for (int i = 0; i < 4; ++i) {
#pragma unroll
        for (int r = 0; r < 4; ++r) {
            const int row = wr * 64 + i * 16 + lq * 4 + r;   // 0..127
            const float bias = b2[row];
#pragma unroll
            for (int j = 0; j < 2; ++j) {
                const int col = bn + wc * 32 + j * 16 + lm;
                const unsigned bb = (unsigned)col / 2000u;
                const unsigned mm = (unsigned)col - bb * 2000u;
                encb[((size_t)bb * 128 + row) * KP8 + mm] = f2fp8(acc[i][j][r] + bias);
            }
        }
    }
}

// ---------------------------------------------------------------- conv GEMM fp8, 128x128 tile, BK=64, 512 threads
// Xt[n][(b,e)] = inv_rs[n] * (simb8 @ encb8^T), bf16 out.
__global__ __launch_bounds__(512) void k_conv(
        const u8* __restrict__ simb, const u8* __restrict__ encb,
        u16* __restrict__ Xt, const float* __restrict__ inv_rs) {
    __shared__ u8 lds[16 * 1024];           // 16 chunks x 1KB (A: 0-7, B: 8-15)
    const int tid = threadIdx.x;
    const int w = tid >> 6, l = tid & 63;   // 8 waves
    const int wr = w & 1, wc = w >> 1;      // wc in [0,4)
    const int bm = blockIdx.x * 128, bn = blockIdx.y * 128;
    const int lm = l & 15, lq = l >> 4;

    f32x4 acc[4][2] = {};

    for (int k0 = 0; k0 < KP8; k0 += 64) {
        __syncthreads();
#pragma unroll
        for (int i = 0; i < 2; ++i) {
            const int idx = w * 2 + i;
            const u8* gp;
            if (idx < 8) {
                int row = bm + idx * 16 + lm;
                row = row < NN ? row : NN - 1;
                gp = simb + (size_t)row * KP8 + k0 + lq * 16;
            } else {
                gp = encb + (size_t)(bn + (idx - 8) * 16 + lm) * KP8 + k0 + lq * 16;
            }
            __builtin_amdgcn_global_load_lds((gptr_t)gp, (lptr_t)(lds + idx * 1024), 16, 0, 0);
        }
        __syncthreads();
        const int fo = ((lq >> 1) << 8) + lm * 16 + (lq & 1) * 8;
        long af[4][2], bf[2][2];
#pragma unroll
        for (int i = 0; i < 4; ++i) {
            af[i][0] = *(const long*)(lds + (wr * 4 + i) * 1024 + fo);
            af[i][1] = *(const long*)(lds + (wr * 4 + i) * 1024 + 512 + fo);
        }
#pragma unroll
        for (int j = 0; j < 2; ++j) {
            bf[j][0] = *(const long*)(lds + (8 + wc * 2 + j) * 1024 + fo);
            bf[j][1] = *(const long*)(lds + (8 + wc * 2 + j) * 1024 + 512 + fo);
        }
#pragma unroll
        for (int i = 0; i < 4; ++i)
#pragma unroll
            for (int j = 0; j < 2; ++j) {
                acc[i][j] = __builtin_amdgcn_mfma_f32_16x16x32_fp8_fp8(af[i][0], bf[j][0], acc[i][j], 0, 0, 0);
                acc[i][j] = __builtin_amdgcn_mfma_f32_16x16x32_fp8_fp8(af[i][1], bf[j][1], acc[i][j], 0, 0, 0);
            }
    }

#pragma unroll
    for (int i = 0; i < 4; ++i) {
#pragma unroll
        for (int r = 0; r < 4; ++r) {
            const int row = bm + wr * 64 + i * 16 + lq * 4 + r;
            if (row >= NN) continue;
            const float rsv = inv_rs[row];
#pragma unroll
            for (int j = 0; j < 2; ++j) {
                const int col = bn + wc * 32 + j * 16 + lm;
                Xt[(size_t)row * 4096 + col] = f2bf(acc[i][j][r] * rsv);
            }
        }
    }
}

// ---------------------------------------------------------------- y0 GEMM: Xt @ Wq1at^T + bq1, dual store bf16 + fp8
__global__ __launch_bounds__(256) void k_y0(
        const u16* __restrict__ A, const u16* __restrict__ Bt,
        u16* __restrict__ C, u8* __restrict__ Cf8,
        const float* __restrict__ bias) {
    __shared__ u16 lds[16 * 512];
    const int tid = threadIdx.x;
    const int w = tid >> 6, l = tid & 63;
    const int wr = w & 1, wc = w >> 1;
    const int bm = blockIdx.x * 128, bn = blockIdx.y * 128;
    const int lm = l & 15, lq = l >> 4;

    f32x4 acc[4][4] = {};

    for (int k0 = 0; k0 < NE; k0 += 32) {
        __syncthreads();
#pragma unroll
        for (int i = 0; i < 4; ++i) {
            const int idx = w * 4 + i;
            const u16* gp;
            if (idx < 8) {
                gp = A + (size_t)(bm + idx * 16 + lm) * NE + k0 + lq * 8;
            } else {
                gp = Bt + (size_t)(bn + (idx - 8) * 16 + lm) * NE + k0 + lq * 8;
            }
            __builtin_amdgcn_global_load_lds((gptr_t)gp, (lptr_t)(lds + idx * 512), 16, 0, 0);
        }
        __syncthreads();
        b16x8 af[4], bf[4];
#pragma unroll
        for (int i = 0; i < 4; ++i) {
            af[i] = *(const b16x8*)(lds + (wr * 4 + i) * 512 + l * 8);
            bf[i] = *(const b16x8*)(lds + (8 + wc * 4 + i) * 512 + l * 8);
        }
#pragma unroll
        for (int fr = 0; fr < 4; ++fr)
#pragma unroll
            for (int fc = 0; fc < 4; ++fc)
                acc[fr][fc] = __builtin_amdgcn_mfma_f32_16x16x32_bf16(af[fr], bf[fc], acc[fr][fc], 0, 0, 0);
    }

#pragma unroll
    for (int fr = 0; fr < 4; ++fr) {
#pragma unroll
        for (int r = 0; r < 4; ++r) {
            const int row = bm + wr * 64 + fr * 16 + lq * 4 + r;
#pragma unroll
            for (int fc = 0; fc < 4; ++fc) {
                const int col = bn + wc * 64 + fc * 16 + lm;
                const float v = acc[fr][fc][r] + bias[col];
                const size_t addr = (size_t)row * NH + col;
                C[addr] = f2bf(v);
                Cf8[addr] = f2fp8(v);
            }
        }
    }
}

// ---------------------------------------------------------------- per-agent kernel
// grid 1024x256 = 4096 waves; wave wg: b=wg&31, ng=wg>>5 (0..127).
// Quarter-wave per node: node n = 4p+qtr, p = ng+128k (k<4, p<500); lane reads 16 fp8.
// Every wave recomputes sam(ag-1) from pin (bit-identical); one float2 out, no atomics.
// Blocks 0..31 additionally finalize agent ag-1 (bf16 y0 at nsel).
__global__ __launch_bounds__(256) void k_agent(
        const u8* __restrict__ y0f8, const u16* __restrict__ y0,
        const float* __restrict__ Wq1, const float* __restrict__ Wq2,
        const float* __restrict__ bq2, float* actions,
        const float2* __restrict__ pin, float2* __restrict__ pout,
        float* __restrict__ out, int ag) {
    __shared__ float sh[256];
    __shared__ float s_sam;
    const int t = threadIdx.x;
    const int lane = t & 63, wave = t >> 6;
    const int wg = blockIdx.x * 4 + wave;
    const int b = wg & 31, ng = wg >> 5;        // ng in [0,128)
    const int hl = lane & 15, qtr = lane >> 4;

    float act[NA];
#pragma unroll
    for (int a = 0; a < NA; ++a) act[a] = actions[b * NA + a];
    if (ag > 0) {
        const float2 p0 = pin[b * NGP + lane];
        const float2 p1 = pin[b * NGP + 64 + lane];
        float se0 = p0.x + p1.x, sn0 = p0.y + p1.y;
#pragma unroll
        for (int m = 32; m > 0; m >>= 1) {
            se0 += __shfl_xor(se0, m); sn0 += __shfl_xor(sn0, m);
        }
        const float sam = fminf(fmaxf(sn0 / se0, 0.0f), 2000.0f);
        act[ag - 1] = sam * (1.0f / ACTION_NORM);
    }
    // ap and w2 slices: h = hl*16 + 0..15
    float ap16[16] = {};
#pragma unroll
    for (int a = 0; a < NA; ++a) {
        const float av = act[a];
        const float4* wq = (const float4*)(Wq1 + (size_t)(NE + a) * NH + hl * 16);
#pragma unroll
        for (int jj = 0; jj < 4; ++jj) {
            const float4 w4 = wq[jj];
            ap16[jj * 4 + 0] = fmaf(av, w4.x, ap16[jj * 4 + 0]);
            ap16[jj * 4 + 1] = fmaf(av, w4.y, ap16[jj * 4 + 1]);
            ap16[jj * 4 + 2] = fmaf(av, w4.z, ap16[jj * 4 + 2]);
            ap16[jj * 4 + 3] = fmaf(av, w4.w, ap16[jj * 4 + 3]);
        }
    }
    float w2v[16];
    {
        const float4* w2p = (const float4*)(Wq2 + hl * 16);
#pragma unroll
        for (int jj = 0; jj < 4; ++jj) {
            const float4 w4 = w2p[jj];
            w2v[jj * 4 + 0] = w4.x; w2v[jj * 4 + 1] = w4.y;
            w2v[jj * 4 + 2] = w4.z; w2v[jj * 4 + 3] = w4.w;
        }
    }

    float se = 0.0f, sn = 0.0f;
#pragma unroll
    for (int k = 0; k < 4; ++k) {
        const int p = ng + k * NGP;
        if (p >= NN / 4) break;
        const int n = 4 * p + qtr;
        const uint4 yv = *(const uint4*)(y0f8 + (((size_t)n * NB + b) << 8) + hl * 16);
        const unsigned dw[4] = {yv.x, yv.y, yv.z, yv.w};
        float q = 0.0f;
#pragma unroll
        for (int d = 0; d < 4; ++d) {
            const auto lo = __builtin_amdgcn_cvt_pk_f32_fp8(dw[d], false);
            const auto hi = __builtin_amdgcn_cvt_pk_f32_fp8(dw[d], true);
            q += fmaxf(lo[0] + ap16[d * 4 + 0], 0.f) * w2v[d * 4 + 0];
            q += fmaxf(lo[1] + ap16[d * 4 + 1], 0.f) * w2v[d * 4 + 1];
            q += fmaxf(hi[0] + ap16[d * 4 + 2], 0.f) * w2v[d * 4 + 2];
            q += fmaxf(hi[1] + ap16[d * 4 + 3], 0.f) * w2v[d * 4 + 3];
        }
#pragma unroll
        for (int off = 1; off < 16; off <<= 1) q += __shfl_xor(q, off);
        const float e = expf(fminf(q, 60.0f));
        se += e; sn += e * (float)n;
    }
    // combine quarters (each quarter's lanes hold identical se,sn)
    se += __shfl_xor(se, 16); sn += __shfl_xor(sn, 16);
    se += __shfl_xor(se, 32); sn += __shfl_xor(sn, 32);
    if (lane == 0) pout[b * NGP + ng] = make_float2(se, sn);

    if (ag > 0 && blockIdx.x < NB) {
        const int bb = blockIdx.x;
        if (wave == 0) {
            const float2 p0 = pin[bb * NGP + lane];
            const float2 p1 = pin[bb * NGP + 64 + lane];
            float a1 = p0.x + p1.x, a2 = p0.y + p1.y;
#pragma unroll
            for (int m = 32; m > 0; m >>= 1) {
                a1 += __shfl_xor(a1, m); a2 += __shfl_xor(a2, m);
            }
            if (lane == 0) s_sam = fminf(fmaxf(a2 / a1, 0.0f), 2000.0f);
        }
        __syncthreads();
        const float sam = s_sam;
        const float samn = sam * (1.0f / ACTION_NORM);
        float apt = 0.0f;
#pragma unroll
        for (int a = 0; a < NA; ++a) {
            const float av = (a == ag - 1) ? samn : actions[bb * NA + a];
            apt = fmaf(av, Wq1[(size_t)(NE + a) * NH + t], apt);
        }
        int nsel = (int)sam; if (nsel > NN - 1) nsel = NN - 1;
        const float yv = bf2f(y0[((size_t)nsel * NB + bb) * NH + t]);
        sh[t] = fmaxf(yv + apt, 0.0f) * Wq2[t];
        __syncthreads();
        for (int s = 128; s > 0; s >>= 1) {
            if (t < s) sh[t] += sh[t + s];
            __syncthreads();
        }
        if (t == 0) {
            out[bb * NA + (ag - 1)] = sh[0] + bq2[0];
            actions[bb * NA + (ag - 1)] = samn;
        }
    }
}

// ---------------------------------------------------------------- tail: finalize agent 7 + chosen
__global__ __launch_bounds__(256) void k_fin(
        const u16* __restrict__ y0, const float* __restrict__ Wq1,
        const float* __restrict__ Wq2, const float* __restrict__ bq2,
        const float* __restrict__ actions, const float2* __restrict__ pin,
        float* __restrict__ out) {
    __shared__ float sh[256];
    __shared__ float s_sam;
    const int bb = blockIdx.x, t = threadIdx.x;
    const int lane = t & 63, wave = t >> 6;
    if (wave == 0) {
        const float2 p0 = pin[bb * NGP + lane];
        const float2 p1 = pin[bb * NGP + 64 + lane];
        float a1 = p0.x + p1.x, a2 = p0.y + p1.y;
#pragma unroll
        for (int m = 32; m > 0; m >>= 1) {
            a1 += __shfl_xor(a1, m); a2 += __shfl_xor(a2, m);
        }
        if (lane == 0) s_sam = fminf(fmaxf(a2 / a1, 0.0f), 2000.0f);
    }
    __syncthreads();
    const float sam = s_sam;
    const float samn = sam * (1.0f / ACTION_NORM);
    float apt = 0.0f;
#pragma unroll
    for (int a = 0; a < NA; ++a) {
        const float av = (a == NA - 1) ? samn : actions[bb * NA + a];
        apt = fmaf(av, Wq1[(size_t)(NE + a) * NH + t], apt);
    }
    int nsel = (int)sam; if (nsel > NN - 1) nsel = NN - 1;
    const float yv = bf2f(y0[((size_t)nsel * NB + bb) * NH + t]);
    sh[t] = fmaxf(yv + apt, 0.0f) * Wq2[t];
    __syncthreads();
    for (int s = 128; s > 0; s >>= 1) {
        if (t < s) sh[t] += sh[t + s];
        __syncthreads();
    }
    if (t == 0) out[bb * NA + (NA - 1)] = sh[0] + bq2[0];
    if (t < NA) {
        const float av = (t == NA - 1) ? samn : actions[bb * NA + t];
        out[NB * NA + bb * NA + t] = (float)(int)(av * ACTION_NORM);
    }
}

// ---------------------------------------------------------------- launch
extern "C" void kernel_launch(void* const* d_in, const int* in_sizes, int n_in,
                              void* d_out, int out_size, void* d_ws, size_t ws_size,
                              hipStream_t stream) {
    const float* state = (const float*)d_in[0];
    const float* dm    = (const float*)d_in[1];
    const float* W1    = (const float*)d_in[2];
    const float* b1    = (const float*)d_in[3];
    const float* W2    = (const float*)d_in[4];
    const float* b2    = (const float*)d_in[5];
    const float* Wq1   = (const float*)d_in[6];
    const float* bq1   = (const float*)d_in[7];
    const float* Wq2   = (const float*)d_in[8];
    const float* bq2   = (const float*)d_in[9];
    const int* fa      = (const int*)d_in[10];
    const int* fid     = (const int*)d_in[11];
    float* out = (float*)d_out;

    char* p = (char*)d_ws;
    u8* simb       = (u8*)p;       p += (size_t)NN * KP8;           // 4.10 MB
    u8* encb       = (u8*)p;       p += (size_t)4096 * KP8;         // 8.39 MB
    float* inv_rs  = (float*)p;    p += 2048 * 4;
    float* pmax    = (float*)p;    p += 1024 * 4;
    float* actions = (float*)p;    p += 256 * 4;
    float2* part0  = (float2*)p;   p += (size_t)NB * NGP * 8;
    float2* part1  = (float2*)p;   p += (size_t)NB * NGP * 8;
    u16* state_b   = (u16*)p;      p += (size_t)2048000 * 2;
    u16* W1t       = (u16*)p;      p += 8192 * 2;
    u16* W2t       = (u16*)p;      p += 32768 * 2;
    u16* Wq1at     = (u16*)p;      p += 32768 * 2;
    u16* h1        = (u16*)p;      p += (size_t)16384000 * 2;       // 32.8 MB
    u16* Xt        = (u16*)p;      p += (size_t)8192000 * 2;        // 16.4 MB
    u16* y0w       = (u16*)p;      p += (size_t)16384000 * 2;       // 32.8 MB
    u8* y0f8       = (u8*)p;       p += (size_t)16384000;           // 16.4 MB

    const int RTOT = NB * NN;  // 64000

    // front: prep + dm partial max + actions init
    k_front<<<PREP_BLOCKS + MAX_BLOCKS + 1, 256, 0, stream>>>(
        state, W1, W2, Wq1, dm, fa, fid,
        state_b, W1t, W2t, Wq1at, encb, pmax, actions);
    // enc1 GEMM + sim (merged)
    k_gemm1s<<<3000, 256, 0, stream>>>(state_b, W1t, h1, b1, dm, pmax, simb, inv_rs);
    // enc2 (fp8 out, (b,e) rows)
    k_enc2<<<dim3(1, RTOT / 128), 512, 0, stream>>>(W2t, h1, encb, b2);
    // conv (fp8): Xt[n][(b,e)] = inv_rs[n] * (simb @ encb^T)
    k_conv<<<dim3(16, 32), 512, 0, stream>>>(simb, encb, Xt, inv_rs);
    // y0 = Xt @ Wq1[:128] + bq1, dual bf16 + fp8 store
    k_y0<<<dim3(RTOT / 128, NH / 128), 256, 0, stream>>>(Xt, Wq1at, y0w, y0f8, bq1);

    // 8-agent loop: one kernel per agent, double-buffered partials
    for (int ag = 0; ag < NA; ++ag) {
        const float2* pin  = (ag & 1) ? part0 : part1;
        float2*       pout = (ag & 1) ? part1 : part0;
        k_agent<<<1024, 256, 0, stream>>>(y0f8, y0w, Wq1, Wq2, bq2, actions,
                                          pin, pout, out, ag);
    }
    // finalize agent 7 (+ chosen); ag=7 wrote part1
    k_fin<<<NB, 256, 0, stream>>>(y0w, Wq1, Wq2, bq2, actions, part1, out);
}